// Round 10
// baseline (519.235 us; speedup 1.0000x reference)
//
#include <hip/hip_runtime.h>
#include <hip/hip_bf16.h>

#define DIM 2048
#define HEAD_DIM 128
#define N_HEADS 16
#define SEQ 2048
#define HID 8192
#define SQKV 6144   // row stride of fused qkv activation

typedef short bf16x8 __attribute__((ext_vector_type(8)));
typedef float f32x4 __attribute__((ext_vector_type(4)));
using bf16 = __hip_bfloat16;

#define MFMA16(a, b, c) __builtin_amdgcn_mfma_f32_16x16x32_bf16(a, b, c, 0, 0, 0)

__device__ __forceinline__ unsigned short f2bu(float f) {
    union { bf16 b; unsigned short u; } cv;
    cv.b = __float2bfloat16(f);
    return cv.u;
}

// async global -> LDS, 16B per lane (dest must be lane-linear per wave)
__device__ __forceinline__ void gl16(const void* g, void* l) {
    __builtin_amdgcn_global_load_lds(
        (const __attribute__((address_space(1))) unsigned int*)g,
        (__attribute__((address_space(3))) unsigned int*)l, 16, 0, 0);
}

// ---------------- rmsnorm (fp32 in -> bf16 out) ----------------
__global__ __launch_bounds__(256) void rmsnorm_bf16_k(
    const float* __restrict__ x, const float* __restrict__ w, bf16* __restrict__ y)
{
    const int row = blockIdx.x;
    const int tid = threadIdx.x;
    const float* xr = x + (size_t)row * DIM;
    float4 v0 = ((const float4*)xr)[tid];
    float4 v1 = ((const float4*)xr)[tid + 256];
    float ss = v0.x*v0.x + v0.y*v0.y + v0.z*v0.z + v0.w*v0.w
             + v1.x*v1.x + v1.y*v1.y + v1.z*v1.z + v1.w*v1.w;
    for (int o = 32; o > 0; o >>= 1) ss += __shfl_down(ss, o);
    __shared__ float red[4];
    if ((tid & 63) == 0) red[tid >> 6] = ss;
    __syncthreads();
    float tot = red[0] + red[1] + red[2] + red[3];
    float r = rsqrtf(tot * (1.0f / DIM) + 1e-6f);
    float4 w0 = ((const float4*)w)[tid];
    float4 w1 = ((const float4*)w)[tid + 256];
    ushort4 o0, o1;
    o0.x = f2bu(v0.x * r * w0.x); o0.y = f2bu(v0.y * r * w0.y);
    o0.z = f2bu(v0.z * r * w0.z); o0.w = f2bu(v0.w * r * w0.w);
    o1.x = f2bu(v1.x * r * w1.x); o1.y = f2bu(v1.y * r * w1.y);
    o1.z = f2bu(v1.z * r * w1.z); o1.w = f2bu(v1.w * r * w1.w);
    ushort4* yr = (ushort4*)(y + (size_t)row * DIM);
    yr[tid] = o0;
    yr[tid + 256] = o1;
}

// ---------------- split-K reduce + residual + rmsnorm (fp32 h out, bf16 fn out) ----------------
__global__ __launch_bounds__(256) void rmsnorm4_k(
    const float* __restrict__ part, const float* __restrict__ x,
    const float* __restrict__ w, float* __restrict__ hout, bf16* __restrict__ y)
{
    const int row = blockIdx.x;
    const int tid = threadIdx.x;
    const size_t base = (size_t)row * DIM;
    const size_t SP = (size_t)SEQ * DIM;
    float4 r0, r1;
    float ss = 0.0f;
    {
        float4 a  = ((const float4*)(x + base))[tid];
        float4 p0 = ((const float4*)(part + base))[tid];
        float4 p1 = ((const float4*)(part + SP + base))[tid];
        float4 p2 = ((const float4*)(part + 2 * SP + base))[tid];
        float4 p3 = ((const float4*)(part + 3 * SP + base))[tid];
        r0.x = a.x + ((p0.x + p1.x) + (p2.x + p3.x));
        r0.y = a.y + ((p0.y + p1.y) + (p2.y + p3.y));
        r0.z = a.z + ((p0.z + p1.z) + (p2.z + p3.z));
        r0.w = a.w + ((p0.w + p1.w) + (p2.w + p3.w));
        ((float4*)(hout + base))[tid] = r0;
        ss += r0.x*r0.x + r0.y*r0.y + r0.z*r0.z + r0.w*r0.w;
    }
    {
        const int t2 = tid + 256;
        float4 a  = ((const float4*)(x + base))[t2];
        float4 p0 = ((const float4*)(part + base))[t2];
        float4 p1 = ((const float4*)(part + SP + base))[t2];
        float4 p2 = ((const float4*)(part + 2 * SP + base))[t2];
        float4 p3 = ((const float4*)(part + 3 * SP + base))[t2];
        r1.x = a.x + ((p0.x + p1.x) + (p2.x + p3.x));
        r1.y = a.y + ((p0.y + p1.y) + (p2.y + p3.y));
        r1.z = a.z + ((p0.z + p1.z) + (p2.z + p3.z));
        r1.w = a.w + ((p0.w + p1.w) + (p2.w + p3.w));
        ((float4*)(hout + base))[t2] = r1;
        ss += r1.x*r1.x + r1.y*r1.y + r1.z*r1.z + r1.w*r1.w;
    }
    for (int o = 32; o > 0; o >>= 1) ss += __shfl_down(ss, o);
    __shared__ float red[4];
    if ((tid & 63) == 0) red[tid >> 6] = ss;
    __syncthreads();
    float tot = red[0] + red[1] + red[2] + red[3];
    float r = rsqrtf(tot * (1.0f / DIM) + 1e-6f);
    float4 w0 = ((const float4*)w)[tid];
    float4 w1 = ((const float4*)w)[tid + 256];
    ushort4 o0, o1;
    o0.x = f2bu(r0.x * r * w0.x); o0.y = f2bu(r0.y * r * w0.y);
    o0.z = f2bu(r0.z * r * w0.z); o0.w = f2bu(r0.w * r * w0.w);
    o1.x = f2bu(r1.x * r * w1.x); o1.y = f2bu(r1.y * r * w1.y);
    o1.z = f2bu(r1.z * r * w1.z); o1.w = f2bu(r1.w * r * w1.w);
    ushort4* yr = (ushort4*)(y + base);
    yr[tid] = o0;
    yr[tid + 256] = o1;
}

// ---------------- split-K reduce + residual (fp32 out) ----------------
__global__ __launch_bounds__(256) void reduce4_k(
    const float* __restrict__ part, const float* __restrict__ h, float* __restrict__ out)
{
    const size_t i = (size_t)blockIdx.x * 256 + threadIdx.x;   // float4 index
    const size_t SP4 = (size_t)SEQ * DIM / 4;
    float4 a  = ((const float4*)h)[i];
    float4 p0 = ((const float4*)part)[i];
    float4 p1 = ((const float4*)part)[i + SP4];
    float4 p2 = ((const float4*)part)[i + 2 * SP4];
    float4 p3 = ((const float4*)part)[i + 3 * SP4];
    float4 r;
    r.x = a.x + ((p0.x + p1.x) + (p2.x + p3.x));
    r.y = a.y + ((p0.y + p1.y) + (p2.y + p3.y));
    r.z = a.z + ((p0.z + p1.z) + (p2.z + p3.z));
    r.w = a.w + ((p0.w + p1.w) + (p2.w + p3.w));
    ((float4*)out)[i] = r;
}

// ---------------- fp32 [R][C] -> bf16 [C][R] transpose-convert ----------------
__global__ __launch_bounds__(256) void convT_f32_bf16_k(
    const float* __restrict__ in, bf16* __restrict__ out, int R, int C)
{
    __shared__ float t[32][33];
    const int tx = threadIdx.x, ty = threadIdx.y;
    const int x0 = blockIdx.x * 32, y0 = blockIdx.y * 32;
#pragma unroll
    for (int i = 0; i < 4; ++i)
        t[ty + i * 8][tx] = in[(size_t)(y0 + ty + i * 8) * C + x0 + tx];
    __syncthreads();
#pragma unroll
    for (int i = 0; i < 4; ++i)
        out[(size_t)(x0 + ty + i * 8) * R + y0 + tx] = __float2bfloat16(t[tx][ty + i * 8]);
}

// 3 square weights -> one [3*DIM][DIM] B^T buffer (z selects wq/wk/wv)
__global__ __launch_bounds__(256) void convT3_f32_bf16_k(
    const float* __restrict__ wq, const float* __restrict__ wk,
    const float* __restrict__ wv, bf16* __restrict__ out)
{
    const int z = blockIdx.z;
    const float* in = z == 0 ? wq : (z == 1 ? wk : wv);
    bf16* o = out + (size_t)z * DIM * DIM;
    __shared__ float t[32][33];
    const int tx = threadIdx.x, ty = threadIdx.y;
    const int x0 = blockIdx.x * 32, y0 = blockIdx.y * 32;
#pragma unroll
    for (int i = 0; i < 4; ++i)
        t[ty + i * 8][tx] = in[(size_t)(y0 + ty + i * 8) * DIM + x0 + tx];
    __syncthreads();
#pragma unroll
    for (int i = 0; i < 4; ++i)
        o[(size_t)(x0 + ty + i * 8) * DIM + y0 + tx] = __float2bfloat16(t[tx][ty + i * 8]);
}

// ---------------- bf16 transpose with src stride (vt[d][s] = in[s][d]) ----------------
__global__ __launch_bounds__(256) void transpose_bf16_k(
    const bf16* __restrict__ in, int istride, bf16* __restrict__ out)
{
    __shared__ unsigned short t[32][33];
    const int tx = threadIdx.x, ty = threadIdx.y;
    const int x = blockIdx.x * 32 + tx;       // d
    const int y0 = blockIdx.y * 32;           // s
    const unsigned short* inu = (const unsigned short*)in;
    unsigned short* outu = (unsigned short*)out;
#pragma unroll
    for (int i = 0; i < 4; ++i)
        t[ty + i * 8][tx] = inu[(size_t)(y0 + ty + i * 8) * istride + x];
    __syncthreads();
    const int x2 = blockIdx.y * 32 + tx;
    const int y2 = blockIdx.x * 32;
#pragma unroll
    for (int i = 0; i < 4; ++i)
        outu[(size_t)(y2 + ty + i * 8) * SEQ + x2] = t[tx][ty + i * 8];
}

// ---------------- RoPE in-place on strided bf16 q,k ----------------
__global__ __launch_bounds__(256) void rope_qk_k(
    bf16* __restrict__ q, bf16* __restrict__ k,
    const float* __restrict__ cosb, const float* __restrict__ sinb)
{
    const int gid = blockIdx.x * 256 + threadIdx.x;   // < SEQ * 1024
    const int s = gid >> 10;
    const int p = gid & 1023;
    const int h = p >> 6, j = p & 63;
    const size_t off = (size_t)s * SQKV + h * HEAD_DIM + 2 * j;
    const float c = cosb[s * 64 + j], sn = sinb[s * 64 + j];
    float xr = __bfloat162float(q[off]), xi = __bfloat162float(q[off + 1]);
    q[off]     = __float2bfloat16(xr * c - xi * sn);
    q[off + 1] = __float2bfloat16(xr * sn + xi * c);
    xr = __bfloat162float(k[off]); xi = __bfloat162float(k[off + 1]);
    k[off]     = __float2bfloat16(xr * c - xi * sn);
    k[off + 1] = __float2bfloat16(xr * sn + xi * c);
}

// ---------------- 256x256 GEMM, m201 8-phase skeleton, BK=64 x2/iter, split-K ----------------
// EP 0: store bf16    EP 2: Cb = silu(other)*acc (in-place ok)    EP 3: fp32 partial store
// LDS (dynamic 128KB): A halves [buf][half][128x64] at (buf*2+half)*16KB; B at +64KB.
// Swizzle byte^=((row&7)<<4); inverse pre-applied on global src of gl16 (rule #21).
// Phase = {stage 1 half-tile, ds_read, barrier, lgkmcnt(0)+sched_barrier, 16 MFMA, barrier}.
// Counted vmcnt(2) at ph4-top & ph8-top: each leaves exactly the 1 newer half-stage, forcing
// the 4 half-stages the NEXT phases consume to have landed; the phase's first barrier
// publishes them block-wide (per-wave vmcnt alone is not sufficient).
template <int EP>
__global__ __launch_bounds__(512, 2) void gemm256_k(
    const bf16* __restrict__ A, const bf16* __restrict__ Bt,
    bf16* __restrict__ Cb, const bf16* other, float* __restrict__ Pf,
    int M, int N, int K, int gx, int ntile, int Ks)
{
    extern __shared__ char smem[];
    const int t512 = threadIdx.x;
    const int w = t512 >> 6, lane = t512 & 63;
    const int lr = lane & 15, lg = lane >> 4;
    const int wm = w >> 2, wn = w & 3;           // 2 x 4 wave grid
    const int bofs = (wn & 1) * 64;              // B row offset inside its half
    const int swz = (lr & 7) << 4;               // ds_read swizzle

    // XCD-bijective block swizzle (m204)
    const int nwg = gridDim.x;                    // = ntile * splitk
    const int q8 = nwg >> 3, r8 = nwg & 7;
    const int xcd = blockIdx.x & 7, seqq = blockIdx.x >> 3;
    const int wgid = (xcd < r8 ? xcd * (q8 + 1) : r8 * (q8 + 1) + (xcd - r8) * q8) + seqq;
    const int split = wgid / ntile;
    const int tile = wgid % ntile;
    // GROUP_M=4 supertiling (M/256 divisible by 4 for all uses)
    const int grp = tile / (4 * gx), rem = tile % (4 * gx);
    const int m0 = (grp * 4 + (rem & 3)) * 256, n0 = (rem >> 2) * 256;
    const int kb0 = split * Ks;
    const int niter = Ks >> 7;                    // 2 K-tiles per iteration (Ks % 128 == 0)

    // staging source pointers (pre-swizzled), advance by kt*64 elements
    const bf16* aS[2][2]; const bf16* bS[2][2];   // [half][c]
    int sOff[2];
#pragma unroll
    for (int c = 0; c < 2; ++c) {
        const int s = (c * 512 + t512) * 16;            // linear byte slot
        const int pp = s ^ (((s >> 7) & 7) << 4);       // nominal position (involution)
        const int row = pp >> 7, colE = (pp & 127) >> 1;
        sOff[c] = s;
#pragma unroll
        for (int hs = 0; hs < 2; ++hs) {
            aS[hs][c] = A  + (size_t)(m0 + hs * 128 + row) * K + kb0 + colE;
            bS[hs][c] = Bt + (size_t)(n0 + hs * 128 + row) * K + kb0 + colE;
        }
    }
    auto stA = [&](int buf, int kt, int hs) {      // one A half-tile: 2 gl16/thread
        char* base = smem + (buf * 2 + hs) * 16384;
        gl16(aS[hs][0] + (kt << 6), base + sOff[0]);
        gl16(aS[hs][1] + (kt << 6), base + sOff[1]);
    };
    auto stB = [&](int buf, int kt, int hs) {      // one B half-tile
        char* base = smem + 65536 + (buf * 2 + hs) * 16384;
        gl16(bS[hs][0] + (kt << 6), base + sOff[0]);
        gl16(bS[hs][1] + (kt << 6), base + sOff[1]);
    };

    // per-wave LDS read bases (loop-invariant)
    const char* A0m = smem + (0 * 2 + wm) * 16384;
    const char* A1m = smem + (1 * 2 + wm) * 16384;
    const char* B0m = smem + 65536 + (0 * 2 + (wn >> 1)) * 16384;
    const char* B1m = smem + 65536 + (1 * 2 + (wn >> 1)) * 16384;

    f32x4 acc[8][4] = {};
    bf16x8 bfr[4][2];
    bf16x8 x0, x1, x2, x3;

#define SBAR __builtin_amdgcn_s_barrier()
#define LGKM0 do { asm volatile("s_waitcnt lgkmcnt(0)" ::: "memory"); \
                   __builtin_amdgcn_sched_barrier(0); } while (0)
#define WVM(n) do { asm volatile("s_waitcnt vmcnt(" #n ")" ::: "memory"); \
                    __builtin_amdgcn_sched_barrier(0); } while (0)
#define LDA4(base, mf0) do { \
    x0 = *(const bf16x8*)((base) + (((mf0) * 16 + lr) * 128) + ((lg * 16) ^ swz)); \
    x1 = *(const bf16x8*)((base) + (((mf0) * 16 + lr) * 128) + ((64 + lg * 16) ^ swz)); \
    x2 = *(const bf16x8*)((base) + ((((mf0) + 1) * 16 + lr) * 128) + ((lg * 16) ^ swz)); \
    x3 = *(const bf16x8*)((base) + ((((mf0) + 1) * 16 + lr) * 128) + ((64 + lg * 16) ^ swz)); \
    } while (0)
#define LDB8(base) do { \
    _Pragma("unroll") \
    for (int nf = 0; nf < 4; ++nf) { \
        bfr[nf][0] = *(const bf16x8*)((base) + ((bofs + nf * 16 + lr) * 128) + ((lg * 16) ^ swz)); \
        bfr[nf][1] = *(const bf16x8*)((base) + ((bofs + nf * 16 + lr) * 128) + ((64 + lg * 16) ^ swz)); \
    } } while (0)
#define MFMA_PH(mf0) do { \
    __builtin_amdgcn_s_setprio(1); \
    _Pragma("unroll") \
    for (int nf = 0; nf < 4; ++nf) { \
        acc[(mf0)][nf]     = MFMA16(x0, bfr[nf][0], acc[(mf0)][nf]); \
        acc[(mf0)][nf]     = MFMA16(x1, bfr[nf][1], acc[(mf0)][nf]); \
        acc[(mf0) + 1][nf] = MFMA16(x2, bfr[nf][0], acc[(mf0) + 1][nf]); \
        acc[(mf0) + 1][nf] = MFMA16(x3, bfr[nf][1], acc[(mf0) + 1][nf]); \
    } \
    __builtin_amdgcn_s_setprio(0); } while (0)

    // prologue: tile0 B+A (8 gl16), tile1 B (4 gl16); tile1 A staged in iter0 ph1/ph2
    stB(0, 0, 0); stB(0, 0, 1); stA(0, 0, 0); stA(0, 0, 1);
    stB(1, 1, 0); stB(1, 1, 1);
    WVM(4);                 // tile0's 8 landed; tile1-B still in flight
    SBAR;                   // publish

    for (int t = 0; t < niter; ++t) {
        const bool pf = (t + 1 < niter);
        const int k1 = 2 * t + 1, k2 = 2 * t + 2, k3 = 2 * t + 3;

        // ---- ph1: K-tile 2t quadrant 0 (+ B of buf0) ----
        stA(1, k1, 0);
        LDB8(B0m);
        LDA4(A0m, 0);
        SBAR; LGKM0; MFMA_PH(0); SBAR;
        // ---- ph2 ----
        stA(1, k1, 1);
        LDA4(A0m, 2);
        SBAR; LGKM0; MFMA_PH(2); SBAR;
        // ---- ph3 ----
        if (pf) stB(0, k2, 0);
        LDA4(A0m, 4);
        SBAR; LGKM0; MFMA_PH(4); SBAR;
        // ---- ph4: wait covers {prev B1 halves, this A1 halves} for ph5-8 ----
        if (pf) { WVM(2); } else { WVM(0); }
        if (pf) stB(0, k2, 1);
        LDA4(A0m, 6);
        SBAR; LGKM0; MFMA_PH(6); SBAR;
        // ---- ph5: K-tile 2t+1 quadrant 0 (+ B of buf1) ----
        if (pf) stA(0, k2, 0);
        LDB8(B1m);
        LDA4(A1m, 0);
        SBAR; LGKM0; MFMA_PH(0); SBAR;
        // ---- ph6 ----
        if (pf) stA(0, k2, 1);
        LDA4(A1m, 2);
        SBAR; LGKM0; MFMA_PH(2); SBAR;
        // ---- ph7 ----
        if (pf) stB(1, k3, 0);
        LDA4(A1m, 4);
        SBAR; LGKM0; MFMA_PH(4); SBAR;
        // ---- ph8: wait covers {this B0',A0'} for next ph1 ----
        if (pf) { WVM(2); stB(1, k3, 1); }
        LDA4(A1m, 6);
        SBAR; LGKM0; MFMA_PH(6); SBAR;
    }
#undef SBAR
#undef LGKM0
#undef WVM
#undef LDA4
#undef LDB8
#undef MFMA_PH

    // ---- epilogue ----
    float* pf_base = Pf + (size_t)split * M * N;
#pragma unroll
    for (int mf = 0; mf < 8; ++mf)
#pragma unroll
        for (int nf = 0; nf < 4; ++nf) {
            const int row = m0 + wm * 128 + mf * 16 + lg * 4;
            const int col = n0 + wn * 64 + nf * 16 + lr;
#pragma unroll
            for (int r = 0; r < 4; ++r) {
                const size_t idx = (size_t)(row + r) * N + col;
                const float v = acc[mf][nf][r];
                if (EP == 0) {
                    Cb[idx] = __float2bfloat16(v);
                } else if (EP == 2) {
                    const float gg = __bfloat162float(other[idx]);
                    const float sg = gg / (1.0f + __expf(-gg));
                    Cb[idx] = __float2bfloat16(sg * v);
                } else {
                    pf_base[idx] = v;
                }
            }
        }
}

// ---------------- causal flash attention: QBLK=64 (4 waves x 16 rows), shared KV tiles ----------------
__global__ __launch_bounds__(256) void attn_fwd_k(
    const bf16* __restrict__ qkv, const bf16* __restrict__ vT, bf16* __restrict__ ctx)
{
    const int tid = threadIdx.x;
    const int w = tid >> 6, lane = tid & 63;
    const int lr = lane & 15, lg = lane >> 4;
    const int h = blockIdx.y;
    const int qidx = (blockIdx.y < 8) ? blockIdx.x : (31 - blockIdx.x);
    const int q0b = qidx * 64;
    const int nt = qidx + 1;                  // 64-row KV tiles (causal)

    __shared__ __align__(16) unsigned short Kt[2][64 * 128];
    __shared__ __align__(16) unsigned short Vt[2][128 * 64];
    __shared__ __align__(16) unsigned short Pp[4][16 * 64];

    const char* kbase = (const char*)(qkv + DIM + h * HEAD_DIM);
    const char* vbase = (const char*)(vT + (size_t)h * HEAD_DIM * SEQ);

    const int krow_c = tid >> 4;
    const int kcolB  = (tid & 15) * 16;
    const int vrow_c = tid >> 3;
    const int vcolB  = (tid & 7) * 16;

    auto stage = [&](int buf, int kb) {
#pragma unroll
        for (int c = 0; c < 4; ++c) {
            const int r = c * 16 + krow_c;
            gl16(kbase + (size_t)(kb + r) * (SQKV * 2) + (kcolB ^ ((r & 7) << 4)),
                 &Kt[buf][c * 2048 + tid * 8]);
        }
#pragma unroll
        for (int c = 0; c < 4; ++c) {
            const int r = c * 32 + vrow_c;
            gl16(vbase + (size_t)r * (SEQ * 2) + kb * 2 + (vcolB ^ ((r & 7) << 4)),
                 &Vt[buf][c * 2048 + tid * 8]);
        }
    };

    bf16x8 qf[4];
    const bf16* qrow = qkv + (size_t)(q0b + w * 16 + lr) * SQKV + h * HEAD_DIM;
#pragma unroll
    for (int dt = 0; dt < 4; ++dt)
        qf[dt] = *(const bf16x8*)(qrow + dt * 32 + lg * 8);

    f32x4 o[8] = {};
    float m[4], l[4];
#pragma unroll
    for (int j = 0; j < 4; ++j) { m[j] = -3e38f; l[j] = 0.0f; }
    const float scale = 0.08838834764831845f;

    stage(0, 0);
    __syncthreads();

    int cur = 0;
    for (int t = 0; t < nt; ++t) {
        const int kb = t * 64;
        if (t + 1 < nt) stage(cur ^ 1, kb + 64);

        f32x4 s[4] = {};
        __builtin_amdgcn_s_setprio(1);
#pragma unroll
        for (int ss = 0; ss < 4; ++ss) {
            const int r = ss * 16 + lr;
            const int sw = (r & 7) << 3;
#pragma unroll
            for (int dt = 0; dt < 4; ++dt) {
                bf16x8 kf = *(const bf16x8*)&Kt[cur][r * 128 + ((dt * 32 + lg * 8) ^ sw)];
                s[ss] = MFMA16(qf[dt], kf, s[ss]);
            }
        }
        __builtin_amdgcn_s_setprio(0);

        float al[4];
#pragma unroll
        for (int j = 0; j < 4; ++j) {
            const int qi = q0b + w * 16 + lg * 4 + j;
            const int prow = lg * 4 + j;
            const int psw = (prow & 7) << 3;
            float a[4];
#pragma unroll
            for (int ss = 0; ss < 4; ++ss)
                a[ss] = s[ss][j] * scale + ((kb + ss * 16 + lr) > qi ? -1e9f : 0.0f);
            float mx = fmaxf(fmaxf(a[0], a[1]), fmaxf(a[2], a[3]));
            mx = fmaxf(mx, __shfl_xor(mx, 1));
            mx = fmaxf(mx, __shfl_xor(mx, 2));
            mx = fmaxf(mx, __shfl_xor(mx, 4));
            mx = fmaxf(mx, __shfl_xor(mx, 8));
            const float mn = fmaxf(m[j], mx);
            const float asc = __expf(m[j] - mn);
            float e0 = __expf(a[0] - mn), e1 = __expf(a[1] - mn);
            float e2 = __expf(a[2] - mn), e3 = __expf(a[3] - mn);
            float rs = (e0 + e1) + (e2 + e3);
            rs += __shfl_xor(rs, 1); rs += __shfl_xor(rs, 2);
            rs += __shfl_xor(rs, 4); rs += __shfl_xor(rs, 8);
            l[j] = l[j] * asc + rs;
            m[j] = mn;
            al[j] = asc;
            Pp[w][prow * 64 + ((lr)      ^ psw)] = f2bu(e0);
            Pp[w][prow * 64 + ((16 + lr) ^ psw)] = f2bu(e1);
            Pp[w][prow * 64 + ((32 + lr) ^ psw)] = f2bu(e2);
            Pp[w][prow * 64 + ((48 + lr) ^ psw)] = f2bu(e3);
        }
#pragma unroll
        for (int d2 = 0; d2 < 8; ++d2)
#pragma unroll
            for (int j = 0; j < 4; ++j) o[d2][j] *= al[j];

        asm volatile("s_waitcnt lgkmcnt(0)" ::: "memory");
        __builtin_amdgcn_sched_barrier(0);
        const int asw = (lr & 7) << 3;
        bf16x8 pa0 = *(const bf16x8*)&Pp[w][lr * 64 + ((lg * 8)      ^ asw)];
        bf16x8 pa1 = *(const bf16x8*)&Pp[w][lr * 64 + ((32 + lg * 8) ^ asw)];

        __builtin_amdgcn_s_setprio(1);
#pragma unroll
        for (int d2 = 0; d2 < 8; ++d2) {
            const int rv = d2 * 16 + lr;
            const int vsw = (rv & 7) << 3;
            bf16x8 vf0 = *(const bf16x8*)&Vt[cur][rv * 64 + ((lg * 8)      ^ vsw)];
            bf16x8 vf1 = *(const bf16x8*)&Vt[cur][rv * 64 + ((32 + lg * 8) ^ vsw)];
            o[d2] = MFMA16(pa0, vf0, o[d2]);
            o[d2] = MFMA16(pa1, vf1, o[d2]);
        }
        __builtin_amdgcn_s_setprio(0);

        __syncthreads();
        cur ^= 1;
    }

#pragma unroll
    for (int j = 0; j < 4; ++j) {
        const float inv = 1.0f / l[j];
        bf16* dst = ctx + (size_t)(q0b + w * 16 + lg * 4 + j) * DIM + h * HEAD_DIM + lr;
#pragma unroll
        for (int d2 = 0; d2 < 8; ++d2)
            dst[d2 * 16] = __float2bfloat16(o[d2][j] * inv);
    }
}

// ---------------- host ----------------
extern "C" void kernel_launch(void* const* d_in, const int* in_sizes, int n_in,
                              void* d_out, int out_size, void* d_ws, size_t ws_size,
                              hipStream_t stream)
{
    const float* x   = (const float*)d_in[0];
    const float* fc  = (const float*)d_in[1];
    const float* fs  = (const float*)d_in[2];
    // d_in[3] = mask (unused; causal computed analytically)
    const float* wq  = (const float*)d_in[4];
    const float* wk  = (const float*)d_in[5];
    const float* wv  = (const float*)d_in[6];
    const float* wo  = (const float*)d_in[7];
    const float* w1  = (const float*)d_in[8];
    const float* w2  = (const float*)d_in[9];
    const float* w3  = (const float*)d_in[10];
    const float* anw = (const float*)d_in[11];
    const float* fnw = (const float*)d_in[12];
    float* out = (float*)d_out;

    char* p = (char*)d_ws;
    auto alloc = [&](size_t n) { char* r = p; p += (n + 255) & ~(size_t)255; return r; };
    bf16* wT  = (bf16*)alloc((size_t)HID * DIM * 2);     // reused per weight group
    bf16* hn  = (bf16*)alloc((size_t)SEQ * DIM * 2);
    bf16* qkv = (bf16*)alloc((size_t)SEQ * SQKV * 2);    // fused q|k|v, stride 6144
    bf16* vt  = (bf16*)alloc((size_t)SEQ * DIM * 2);
    bf16* ctx = (bf16*)alloc((size_t)SEQ * DIM * 2);
    bf16* fn  = (bf16*)alloc((size_t)SEQ * DIM * 2);
    float* h  = (float*)alloc((size_t)SEQ * DIM * 4);
    bf16* g   = (bf16*)alloc((size_t)SEQ * HID * 2);
    float* sk = (float*)alloc((size_t)4 * SEQ * DIM * 4);  // split-K partials (64MB)

    const dim3 tb32(32, 8);
    const int LDS256 = 131072;
    (void)hipFuncSetAttribute((const void*)gemm256_k<0>,
        hipFuncAttributeMaxDynamicSharedMemorySize, LDS256);
    (void)hipFuncSetAttribute((const void*)gemm256_k<2>,
        hipFuncAttributeMaxDynamicSharedMemorySize, LDS256);
    (void)hipFuncSetAttribute((const void*)gemm256_k<3>,
        hipFuncAttributeMaxDynamicSharedMemorySize, LDS256);

    rmsnorm_bf16_k<<<SEQ, 256, 0, stream>>>(x, anw, hn);

    // fused QKV: wT = [wq^T; wk^T; wv^T] (6144x2048) -> qkv[2048][6144]
    convT3_f32_bf16_k<<<dim3(DIM / 32, DIM / 32, 3), tb32, 0, stream>>>(wq, wk, wv, wT);
    gemm256_k<0><<<(SEQ / 256) * (SQKV / 256), 512, LDS256, stream>>>(
        hn, wT, qkv, nullptr, nullptr, SEQ, SQKV, DIM, SQKV / 256, (SEQ / 256) * (SQKV / 256), DIM);

    rope_qk_k<<<(SEQ * 1024) / 256, 256, 0, stream>>>(qkv, qkv + DIM, fc, fs);
    transpose_bf16_k<<<dim3(DIM / 32, SEQ / 32), tb32, 0, stream>>>(qkv + 2 * DIM, SQKV, vt);

    attn_fwd_k<<<dim3(SEQ / 64, N_HEADS), 256, 0, stream>>>(qkv, vt, ctx);

    // h = x + ctx @ wo : split-K=4 (Ks=512) -> partials, fused reduce+residual+rmsnorm
    convT_f32_bf16_k<<<dim3(DIM / 32, DIM / 32), tb32, 0, stream>>>(wo, wT, DIM, DIM);
    gemm256_k<3><<<(SEQ / 256) * (DIM / 256) * 4, 512, LDS256, stream>>>(
        ctx, wT, nullptr, nullptr, sk, SEQ, DIM, DIM, DIM / 256, (SEQ / 256) * (DIM / 256), 512);
    rmsnorm4_k<<<SEQ, 256, 0, stream>>>(sk, x, fnw, h, fn);

    convT_f32_bf16_k<<<dim3(HID / 32, DIM / 32), tb32, 0, stream>>>(w1, wT, DIM, HID);
    gemm256_k<0><<<(SEQ / 256) * (HID / 256), 512, LDS256, stream>>>(
        fn, wT, g, nullptr, nullptr, SEQ, HID, DIM, HID / 256, (SEQ / 256) * (HID / 256), DIM);
    convT_f32_bf16_k<<<dim3(HID / 32, DIM / 32), tb32, 0, stream>>>(w3, wT, DIM, HID);
    gemm256_k<2><<<(SEQ / 256) * (HID / 256), 512, LDS256, stream>>>(
        fn, wT, g, g, nullptr, SEQ, HID, DIM, HID / 256, (SEQ / 256) * (HID / 256), DIM);

    // out = h + g @ w2 : split-K=4 (Ks=2048) -> partials, reduce+residual
    convT_f32_bf16_k<<<dim3(DIM / 32, HID / 32), tb32, 0, stream>>>(w2, wT, HID, DIM);
    gemm256_k<3><<<(SEQ / 256) * (DIM / 256) * 4, 512, LDS256, stream>>>(
        g, wT, nullptr, nullptr, sk, SEQ, DIM, HID, DIM / 256, (SEQ / 256) * (DIM / 256), 2048);
    reduce4_k<<<(SEQ * DIM / 4) / 256, 256, 0, stream>>>(sk, h, out);
}

// Round 11
// 510.282 us; speedup vs baseline: 1.0175x; 1.0175x over previous
//
#include <hip/hip_runtime.h>
#include <hip/hip_bf16.h>

#define DIM 2048
#define HEAD_DIM 128
#define N_HEADS 16
#define SEQ 2048
#define HID 8192
#define SQKV 6144   // row stride of fused qkv activation

typedef short bf16x8 __attribute__((ext_vector_type(8)));
typedef float f32x4 __attribute__((ext_vector_type(4)));
using bf16 = __hip_bfloat16;

#define MFMA16(a, b, c) __builtin_amdgcn_mfma_f32_16x16x32_bf16(a, b, c, 0, 0, 0)

__device__ __forceinline__ unsigned short f2bu(float f) {
    union { bf16 b; unsigned short u; } cv;
    cv.b = __float2bfloat16(f);
    return cv.u;
}

// async global -> LDS, 16B per lane (dest must be lane-linear per wave)
__device__ __forceinline__ void gl16(const void* g, void* l) {
    __builtin_amdgcn_global_load_lds(
        (const __attribute__((address_space(1))) unsigned int*)g,
        (__attribute__((address_space(3))) unsigned int*)l, 16, 0, 0);
}

// ---------------- rmsnorm (fp32 in -> bf16 out) ----------------
__global__ __launch_bounds__(256) void rmsnorm_bf16_k(
    const float* __restrict__ x, const float* __restrict__ w, bf16* __restrict__ y)
{
    const int row = blockIdx.x;
    const int tid = threadIdx.x;
    const float* xr = x + (size_t)row * DIM;
    float4 v0 = ((const float4*)xr)[tid];
    float4 v1 = ((const float4*)xr)[tid + 256];
    float ss = v0.x*v0.x + v0.y*v0.y + v0.z*v0.z + v0.w*v0.w
             + v1.x*v1.x + v1.y*v1.y + v1.z*v1.z + v1.w*v1.w;
    for (int o = 32; o > 0; o >>= 1) ss += __shfl_down(ss, o);
    __shared__ float red[4];
    if ((tid & 63) == 0) red[tid >> 6] = ss;
    __syncthreads();
    float tot = red[0] + red[1] + red[2] + red[3];
    float r = rsqrtf(tot * (1.0f / DIM) + 1e-6f);
    float4 w0 = ((const float4*)w)[tid];
    float4 w1 = ((const float4*)w)[tid + 256];
    ushort4 o0, o1;
    o0.x = f2bu(v0.x * r * w0.x); o0.y = f2bu(v0.y * r * w0.y);
    o0.z = f2bu(v0.z * r * w0.z); o0.w = f2bu(v0.w * r * w0.w);
    o1.x = f2bu(v1.x * r * w1.x); o1.y = f2bu(v1.y * r * w1.y);
    o1.z = f2bu(v1.z * r * w1.z); o1.w = f2bu(v1.w * r * w1.w);
    ushort4* yr = (ushort4*)(y + (size_t)row * DIM);
    yr[tid] = o0;
    yr[tid + 256] = o1;
}

// ---------------- split-K reduce + residual + rmsnorm (fp32 h out, bf16 fn out) ----------------
__global__ __launch_bounds__(256) void rmsnorm4_k(
    const float* __restrict__ part, const float* __restrict__ x,
    const float* __restrict__ w, float* __restrict__ hout, bf16* __restrict__ y)
{
    const int row = blockIdx.x;
    const int tid = threadIdx.x;
    const size_t base = (size_t)row * DIM;
    const size_t SP = (size_t)SEQ * DIM;
    float4 r0, r1;
    float ss = 0.0f;
    {
        float4 a  = ((const float4*)(x + base))[tid];
        float4 p0 = ((const float4*)(part + base))[tid];
        float4 p1 = ((const float4*)(part + SP + base))[tid];
        float4 p2 = ((const float4*)(part + 2 * SP + base))[tid];
        float4 p3 = ((const float4*)(part + 3 * SP + base))[tid];
        r0.x = a.x + ((p0.x + p1.x) + (p2.x + p3.x));
        r0.y = a.y + ((p0.y + p1.y) + (p2.y + p3.y));
        r0.z = a.z + ((p0.z + p1.z) + (p2.z + p3.z));
        r0.w = a.w + ((p0.w + p1.w) + (p2.w + p3.w));
        ((float4*)(hout + base))[tid] = r0;
        ss += r0.x*r0.x + r0.y*r0.y + r0.z*r0.z + r0.w*r0.w;
    }
    {
        const int t2 = tid + 256;
        float4 a  = ((const float4*)(x + base))[t2];
        float4 p0 = ((const float4*)(part + base))[t2];
        float4 p1 = ((const float4*)(part + SP + base))[t2];
        float4 p2 = ((const float4*)(part + 2 * SP + base))[t2];
        float4 p3 = ((const float4*)(part + 3 * SP + base))[t2];
        r1.x = a.x + ((p0.x + p1.x) + (p2.x + p3.x));
        r1.y = a.y + ((p0.y + p1.y) + (p2.y + p3.y));
        r1.z = a.z + ((p0.z + p1.z) + (p2.z + p3.z));
        r1.w = a.w + ((p0.w + p1.w) + (p2.w + p3.w));
        ((float4*)(hout + base))[t2] = r1;
        ss += r1.x*r1.x + r1.y*r1.y + r1.z*r1.z + r1.w*r1.w;
    }
    for (int o = 32; o > 0; o >>= 1) ss += __shfl_down(ss, o);
    __shared__ float red[4];
    if ((tid & 63) == 0) red[tid >> 6] = ss;
    __syncthreads();
    float tot = red[0] + red[1] + red[2] + red[3];
    float r = rsqrtf(tot * (1.0f / DIM) + 1e-6f);
    float4 w0 = ((const float4*)w)[tid];
    float4 w1 = ((const float4*)w)[tid + 256];
    ushort4 o0, o1;
    o0.x = f2bu(r0.x * r * w0.x); o0.y = f2bu(r0.y * r * w0.y);
    o0.z = f2bu(r0.z * r * w0.z); o0.w = f2bu(r0.w * r * w0.w);
    o1.x = f2bu(r1.x * r * w1.x); o1.y = f2bu(r1.y * r * w1.y);
    o1.z = f2bu(r1.z * r * w1.z); o1.w = f2bu(r1.w * r * w1.w);
    ushort4* yr = (ushort4*)(y + base);
    yr[tid] = o0;
    yr[tid + 256] = o1;
}

// ---------------- split-K reduce + residual (fp32 out) ----------------
__global__ __launch_bounds__(256) void reduce4_k(
    const float* __restrict__ part, const float* __restrict__ h, float* __restrict__ out)
{
    const size_t i = (size_t)blockIdx.x * 256 + threadIdx.x;   // float4 index
    const size_t SP4 = (size_t)SEQ * DIM / 4;
    float4 a  = ((const float4*)h)[i];
    float4 p0 = ((const float4*)part)[i];
    float4 p1 = ((const float4*)part)[i + SP4];
    float4 p2 = ((const float4*)part)[i + 2 * SP4];
    float4 p3 = ((const float4*)part)[i + 3 * SP4];
    float4 r;
    r.x = a.x + ((p0.x + p1.x) + (p2.x + p3.x));
    r.y = a.y + ((p0.y + p1.y) + (p2.y + p3.y));
    r.z = a.z + ((p0.z + p1.z) + (p2.z + p3.z));
    r.w = a.w + ((p0.w + p1.w) + (p2.w + p3.w));
    ((float4*)out)[i] = r;
}

// ---------------- fp32 [R][C] -> bf16 [C][R] transpose-convert ----------------
__global__ __launch_bounds__(256) void convT_f32_bf16_k(
    const float* __restrict__ in, bf16* __restrict__ out, int R, int C)
{
    __shared__ float t[32][33];
    const int tx = threadIdx.x, ty = threadIdx.y;
    const int x0 = blockIdx.x * 32, y0 = blockIdx.y * 32;
#pragma unroll
    for (int i = 0; i < 4; ++i)
        t[ty + i * 8][tx] = in[(size_t)(y0 + ty + i * 8) * C + x0 + tx];
    __syncthreads();
#pragma unroll
    for (int i = 0; i < 4; ++i)
        out[(size_t)(x0 + ty + i * 8) * R + y0 + tx] = __float2bfloat16(t[tx][ty + i * 8]);
}

// 3 square weights -> one [3*DIM][DIM] B^T buffer (z selects wq/wk/wv)
__global__ __launch_bounds__(256) void convT3_f32_bf16_k(
    const float* __restrict__ wq, const float* __restrict__ wk,
    const float* __restrict__ wv, bf16* __restrict__ out)
{
    const int z = blockIdx.z;
    const float* in = z == 0 ? wq : (z == 1 ? wk : wv);
    bf16* o = out + (size_t)z * DIM * DIM;
    __shared__ float t[32][33];
    const int tx = threadIdx.x, ty = threadIdx.y;
    const int x0 = blockIdx.x * 32, y0 = blockIdx.y * 32;
#pragma unroll
    for (int i = 0; i < 4; ++i)
        t[ty + i * 8][tx] = in[(size_t)(y0 + ty + i * 8) * DIM + x0 + tx];
    __syncthreads();
#pragma unroll
    for (int i = 0; i < 4; ++i)
        o[(size_t)(x0 + ty + i * 8) * DIM + y0 + tx] = __float2bfloat16(t[tx][ty + i * 8]);
}

// ---------------- bf16 transpose with src stride (vt[d][s] = in[s][d]) ----------------
__global__ __launch_bounds__(256) void transpose_bf16_k(
    const bf16* __restrict__ in, int istride, bf16* __restrict__ out)
{
    __shared__ unsigned short t[32][33];
    const int tx = threadIdx.x, ty = threadIdx.y;
    const int x = blockIdx.x * 32 + tx;       // d
    const int y0 = blockIdx.y * 32;           // s
    const unsigned short* inu = (const unsigned short*)in;
    unsigned short* outu = (unsigned short*)out;
#pragma unroll
    for (int i = 0; i < 4; ++i)
        t[ty + i * 8][tx] = inu[(size_t)(y0 + ty + i * 8) * istride + x];
    __syncthreads();
    const int x2 = blockIdx.y * 32 + tx;
    const int y2 = blockIdx.x * 32;
#pragma unroll
    for (int i = 0; i < 4; ++i)
        outu[(size_t)(y2 + ty + i * 8) * SEQ + x2] = t[tx][ty + i * 8];
}

// ---------------- RoPE in-place on strided bf16 q,k ----------------
__global__ __launch_bounds__(256) void rope_qk_k(
    bf16* __restrict__ q, bf16* __restrict__ k,
    const float* __restrict__ cosb, const float* __restrict__ sinb)
{
    const int gid = blockIdx.x * 256 + threadIdx.x;   // < SEQ * 1024
    const int s = gid >> 10;
    const int p = gid & 1023;
    const int h = p >> 6, j = p & 63;
    const size_t off = (size_t)s * SQKV + h * HEAD_DIM + 2 * j;
    const float c = cosb[s * 64 + j], sn = sinb[s * 64 + j];
    float xr = __bfloat162float(q[off]), xi = __bfloat162float(q[off + 1]);
    q[off]     = __float2bfloat16(xr * c - xi * sn);
    q[off + 1] = __float2bfloat16(xr * sn + xi * c);
    xr = __bfloat162float(k[off]); xi = __bfloat162float(k[off + 1]);
    k[off]     = __float2bfloat16(xr * c - xi * sn);
    k[off + 1] = __float2bfloat16(xr * sn + xi * c);
}

// ---------------- 256x256 GEMM, m201 8-phase skeleton, BK=64 x2/iter, split-K ----------------
// EP 0: store bf16    EP 2: Cb = silu(other)*acc (in-place ok)    EP 3: fp32 partial store
// LDS (dynamic 128KB): A halves [buf][half][128x64] at (buf*2+half)*16KB; B at +64KB.
// Swizzle byte^=((row&7)<<4); inverse pre-applied on global src of gl16 (rule #21).
// R11: launch_bounds(512,1) (LDS already caps 1 block/CU; frees register allocator),
// no setprio (m190: hurts lockstep GEMM), m201-exact intra-phase order (reads->stage->bar).
template <int EP>
__global__ __launch_bounds__(512, 1) void gemm256_k(
    const bf16* __restrict__ A, const bf16* __restrict__ Bt,
    bf16* __restrict__ Cb, const bf16* other, float* __restrict__ Pf,
    int M, int N, int K, int gx, int ntile, int Ks)
{
    extern __shared__ char smem[];
    const int t512 = threadIdx.x;
    const int w = t512 >> 6, lane = t512 & 63;
    const int lr = lane & 15, lg = lane >> 4;
    const int wm = w >> 2, wn = w & 3;           // 2 x 4 wave grid
    const int bofs = (wn & 1) * 64;              // B row offset inside its half
    const int swz = (lr & 7) << 4;               // ds_read swizzle

    // XCD-bijective block swizzle (m204)
    const int nwg = gridDim.x;                    // = ntile * splitk
    const int q8 = nwg >> 3, r8 = nwg & 7;
    const int xcd = blockIdx.x & 7, seqq = blockIdx.x >> 3;
    const int wgid = (xcd < r8 ? xcd * (q8 + 1) : r8 * (q8 + 1) + (xcd - r8) * q8) + seqq;
    const int split = wgid / ntile;
    const int tile = wgid % ntile;
    // GROUP_M=4 supertiling (M/256 divisible by 4 for all uses)
    const int grp = tile / (4 * gx), rem = tile % (4 * gx);
    const int m0 = (grp * 4 + (rem & 3)) * 256, n0 = (rem >> 2) * 256;
    const int kb0 = split * Ks;
    const int niter = Ks >> 7;                    // 2 K-tiles per iteration (Ks % 128 == 0)

    // staging source pointers (pre-swizzled), advance by kt*64 elements
    const bf16* aS[2][2]; const bf16* bS[2][2];   // [half][c]
    int sOff[2];
#pragma unroll
    for (int c = 0; c < 2; ++c) {
        const int s = (c * 512 + t512) * 16;            // linear byte slot
        const int pp = s ^ (((s >> 7) & 7) << 4);       // nominal position (involution)
        const int row = pp >> 7, colE = (pp & 127) >> 1;
        sOff[c] = s;
#pragma unroll
        for (int hs = 0; hs < 2; ++hs) {
            aS[hs][c] = A  + (size_t)(m0 + hs * 128 + row) * K + kb0 + colE;
            bS[hs][c] = Bt + (size_t)(n0 + hs * 128 + row) * K + kb0 + colE;
        }
    }
    auto stA = [&](int buf, int kt, int hs) {      // one A half-tile: 2 gl16/thread
        char* base = smem + (buf * 2 + hs) * 16384;
        gl16(aS[hs][0] + (kt << 6), base + sOff[0]);
        gl16(aS[hs][1] + (kt << 6), base + sOff[1]);
    };
    auto stB = [&](int buf, int kt, int hs) {      // one B half-tile
        char* base = smem + 65536 + (buf * 2 + hs) * 16384;
        gl16(bS[hs][0] + (kt << 6), base + sOff[0]);
        gl16(bS[hs][1] + (kt << 6), base + sOff[1]);
    };

    // per-wave LDS read bases (loop-invariant)
    const char* A0m = smem + (0 * 2 + wm) * 16384;
    const char* A1m = smem + (1 * 2 + wm) * 16384;
    const char* B0m = smem + 65536 + (0 * 2 + (wn >> 1)) * 16384;
    const char* B1m = smem + 65536 + (1 * 2 + (wn >> 1)) * 16384;

    f32x4 acc[8][4] = {};
    bf16x8 bfr[4][2];
    bf16x8 x0, x1, x2, x3;

#define SBAR __builtin_amdgcn_s_barrier()
#define LGKM0 do { asm volatile("s_waitcnt lgkmcnt(0)" ::: "memory"); \
                   __builtin_amdgcn_sched_barrier(0); } while (0)
#define WVM(n) do { asm volatile("s_waitcnt vmcnt(" #n ")" ::: "memory"); \
                    __builtin_amdgcn_sched_barrier(0); } while (0)
#define LDA4(base, mf0) do { \
    x0 = *(const bf16x8*)((base) + (((mf0) * 16 + lr) * 128) + ((lg * 16) ^ swz)); \
    x1 = *(const bf16x8*)((base) + (((mf0) * 16 + lr) * 128) + ((64 + lg * 16) ^ swz)); \
    x2 = *(const bf16x8*)((base) + ((((mf0) + 1) * 16 + lr) * 128) + ((lg * 16) ^ swz)); \
    x3 = *(const bf16x8*)((base) + ((((mf0) + 1) * 16 + lr) * 128) + ((64 + lg * 16) ^ swz)); \
    } while (0)
#define LDB8(base) do { \
    _Pragma("unroll") \
    for (int nf = 0; nf < 4; ++nf) { \
        bfr[nf][0] = *(const bf16x8*)((base) + ((bofs + nf * 16 + lr) * 128) + ((lg * 16) ^ swz)); \
        bfr[nf][1] = *(const bf16x8*)((base) + ((bofs + nf * 16 + lr) * 128) + ((64 + lg * 16) ^ swz)); \
    } } while (0)
#define MFMA_PH(mf0) do { \
    _Pragma("unroll") \
    for (int nf = 0; nf < 4; ++nf) { \
        acc[(mf0)][nf]     = MFMA16(x0, bfr[nf][0], acc[(mf0)][nf]); \
        acc[(mf0)][nf]     = MFMA16(x1, bfr[nf][1], acc[(mf0)][nf]); \
        acc[(mf0) + 1][nf] = MFMA16(x2, bfr[nf][0], acc[(mf0) + 1][nf]); \
        acc[(mf0) + 1][nf] = MFMA16(x3, bfr[nf][1], acc[(mf0) + 1][nf]); \
    } } while (0)

    // prologue: tile0 B+A (8 gl16), tile1 B (4 gl16); tile1 A staged in iter0 ph1/ph2
    stB(0, 0, 0); stB(0, 0, 1); stA(0, 0, 0); stA(0, 0, 1);
    stB(1, 1, 0); stB(1, 1, 1);
    WVM(4);                 // tile0's 8 landed; tile1-B still in flight
    SBAR;                   // publish

    for (int t = 0; t < niter; ++t) {
        const bool pf = (t + 1 < niter);
        const int k1 = 2 * t + 1, k2 = 2 * t + 2, k3 = 2 * t + 3;

        // ---- ph1: K-tile 2t quadrant 0 (+ stage A of buf1) ----
        LDB8(B0m);
        LDA4(A0m, 0);
        stA(1, k1, 0);
        SBAR; LGKM0; MFMA_PH(0); SBAR;
        // ---- ph2 ----
        LDA4(A0m, 2);
        stA(1, k1, 1);
        SBAR; LGKM0; MFMA_PH(2); SBAR;
        // ---- ph3 ----
        LDA4(A0m, 4);
        if (pf) stB(0, k2, 0);
        SBAR; LGKM0; MFMA_PH(4); SBAR;
        // ---- ph4: wait covers {prev B1 halves, this A1 halves} for ph5-8 ----
        if (pf) { WVM(2); } else { WVM(0); }
        LDA4(A0m, 6);
        if (pf) stB(0, k2, 1);
        SBAR; LGKM0; MFMA_PH(6); SBAR;
        // ---- ph5: K-tile 2t+1 quadrant 0 (+ stage A of buf0) ----
        LDB8(B1m);
        LDA4(A1m, 0);
        if (pf) stA(0, k2, 0);
        SBAR; LGKM0; MFMA_PH(0); SBAR;
        // ---- ph6 ----
        LDA4(A1m, 2);
        if (pf) stA(0, k2, 1);
        SBAR; LGKM0; MFMA_PH(2); SBAR;
        // ---- ph7 ----
        LDA4(A1m, 4);
        if (pf) stB(1, k3, 0);
        SBAR; LGKM0; MFMA_PH(4); SBAR;
        // ---- ph8: wait covers {this B0',A0'} for next ph1 ----
        if (pf) WVM(2);
        LDA4(A1m, 6);
        if (pf) stB(1, k3, 1);
        SBAR; LGKM0; MFMA_PH(6); SBAR;
    }
#undef SBAR
#undef LGKM0
#undef WVM
#undef LDA4
#undef LDB8
#undef MFMA_PH

    // ---- epilogue ----
    float* pf_base = Pf + (size_t)split * M * N;
#pragma unroll
    for (int mf = 0; mf < 8; ++mf)
#pragma unroll
        for (int nf = 0; nf < 4; ++nf) {
            const int row = m0 + wm * 128 + mf * 16 + lg * 4;
            const int col = n0 + wn * 64 + nf * 16 + lr;
#pragma unroll
            for (int r = 0; r < 4; ++r) {
                const size_t idx = (size_t)(row + r) * N + col;
                const float v = acc[mf][nf][r];
                if (EP == 0) {
                    Cb[idx] = __float2bfloat16(v);
                } else if (EP == 2) {
                    const float gg = __bfloat162float(other[idx]);
                    const float sg = gg / (1.0f + __expf(-gg));
                    Cb[idx] = __float2bfloat16(sg * v);
                } else {
                    pf_base[idx] = v;
                }
            }
        }
}

// ---------------- causal flash attention: QBLK=64 (4 waves x 16 rows), shared KV tiles ----------------
__global__ __launch_bounds__(256) void attn_fwd_k(
    const bf16* __restrict__ qkv, const bf16* __restrict__ vT, bf16* __restrict__ ctx)
{
    const int tid = threadIdx.x;
    const int w = tid >> 6, lane = tid & 63;
    const int lr = lane & 15, lg = lane >> 4;
    const int h = blockIdx.y;
    const int qidx = (blockIdx.y < 8) ? blockIdx.x : (31 - blockIdx.x);
    const int q0b = qidx * 64;
    const int nt = qidx + 1;                  // 64-row KV tiles (causal)

    __shared__ __align__(16) unsigned short Kt[2][64 * 128];
    __shared__ __align__(16) unsigned short Vt[2][128 * 64];
    __shared__ __align__(16) unsigned short Pp[4][16 * 64];

    const char* kbase = (const char*)(qkv + DIM + h * HEAD_DIM);
    const char* vbase = (const char*)(vT + (size_t)h * HEAD_DIM * SEQ);

    const int krow_c = tid >> 4;
    const int kcolB  = (tid & 15) * 16;
    const int vrow_c = tid >> 3;
    const int vcolB  = (tid & 7) * 16;

    auto stage = [&](int buf, int kb) {
#pragma unroll
        for (int c = 0; c < 4; ++c) {
            const int r = c * 16 + krow_c;
            gl16(kbase + (size_t)(kb + r) * (SQKV * 2) + (kcolB ^ ((r & 7) << 4)),
                 &Kt[buf][c * 2048 + tid * 8]);
        }
#pragma unroll
        for (int c = 0; c < 4; ++c) {
            const int r = c * 32 + vrow_c;
            gl16(vbase + (size_t)r * (SEQ * 2) + kb * 2 + (vcolB ^ ((r & 7) << 4)),
                 &Vt[buf][c * 2048 + tid * 8]);
        }
    };

    bf16x8 qf[4];
    const bf16* qrow = qkv + (size_t)(q0b + w * 16 + lr) * SQKV + h * HEAD_DIM;
#pragma unroll
    for (int dt = 0; dt < 4; ++dt)
        qf[dt] = *(const bf16x8*)(qrow + dt * 32 + lg * 8);

    f32x4 o[8] = {};
    float m[4], l[4];
#pragma unroll
    for (int j = 0; j < 4; ++j) { m[j] = -3e38f; l[j] = 0.0f; }
    const float scale = 0.08838834764831845f;

    stage(0, 0);
    __syncthreads();

    int cur = 0;
    for (int t = 0; t < nt; ++t) {
        const int kb = t * 64;
        if (t + 1 < nt) stage(cur ^ 1, kb + 64);

        f32x4 s[4] = {};
        __builtin_amdgcn_s_setprio(1);
#pragma unroll
        for (int ss = 0; ss < 4; ++ss) {
            const int r = ss * 16 + lr;
            const int sw = (r & 7) << 3;
#pragma unroll
            for (int dt = 0; dt < 4; ++dt) {
                bf16x8 kf = *(const bf16x8*)&Kt[cur][r * 128 + ((dt * 32 + lg * 8) ^ sw)];
                s[ss] = MFMA16(qf[dt], kf, s[ss]);
            }
        }
        __builtin_amdgcn_s_setprio(0);

        float al[4];
#pragma unroll
        for (int j = 0; j < 4; ++j) {
            const int qi = q0b + w * 16 + lg * 4 + j;
            const int prow = lg * 4 + j;
            const int psw = (prow & 7) << 3;
            float a[4];
#pragma unroll
            for (int ss = 0; ss < 4; ++ss)
                a[ss] = s[ss][j] * scale + ((kb + ss * 16 + lr) > qi ? -1e9f : 0.0f);
            float mx = fmaxf(fmaxf(a[0], a[1]), fmaxf(a[2], a[3]));
            mx = fmaxf(mx, __shfl_xor(mx, 1));
            mx = fmaxf(mx, __shfl_xor(mx, 2));
            mx = fmaxf(mx, __shfl_xor(mx, 4));
            mx = fmaxf(mx, __shfl_xor(mx, 8));
            const float mn = fmaxf(m[j], mx);
            const float asc = __expf(m[j] - mn);
            float e0 = __expf(a[0] - mn), e1 = __expf(a[1] - mn);
            float e2 = __expf(a[2] - mn), e3 = __expf(a[3] - mn);
            float rs = (e0 + e1) + (e2 + e3);
            rs += __shfl_xor(rs, 1); rs += __shfl_xor(rs, 2);
            rs += __shfl_xor(rs, 4); rs += __shfl_xor(rs, 8);
            l[j] = l[j] * asc + rs;
            m[j] = mn;
            al[j] = asc;
            Pp[w][prow * 64 + ((lr)      ^ psw)] = f2bu(e0);
            Pp[w][prow * 64 + ((16 + lr) ^ psw)] = f2bu(e1);
            Pp[w][prow * 64 + ((32 + lr) ^ psw)] = f2bu(e2);
            Pp[w][prow * 64 + ((48 + lr) ^ psw)] = f2bu(e3);
        }
#pragma unroll
        for (int d2 = 0; d2 < 8; ++d2)
#pragma unroll
            for (int j = 0; j < 4; ++j) o[d2][j] *= al[j];

        asm volatile("s_waitcnt lgkmcnt(0)" ::: "memory");
        __builtin_amdgcn_sched_barrier(0);
        const int asw = (lr & 7) << 3;
        bf16x8 pa0 = *(const bf16x8*)&Pp[w][lr * 64 + ((lg * 8)      ^ asw)];
        bf16x8 pa1 = *(const bf16x8*)&Pp[w][lr * 64 + ((32 + lg * 8) ^ asw)];

        __builtin_amdgcn_s_setprio(1);
#pragma unroll
        for (int d2 = 0; d2 < 8; ++d2) {
            const int rv = d2 * 16 + lr;
            const int vsw = (rv & 7) << 3;
            bf16x8 vf0 = *(const bf16x8*)&Vt[cur][rv * 64 + ((lg * 8)      ^ vsw)];
            bf16x8 vf1 = *(const bf16x8*)&Vt[cur][rv * 64 + ((32 + lg * 8) ^ vsw)];
            o[d2] = MFMA16(pa0, vf0, o[d2]);
            o[d2] = MFMA16(pa1, vf1, o[d2]);
        }
        __builtin_amdgcn_s_setprio(0);

        __syncthreads();
        cur ^= 1;
    }

#pragma unroll
    for (int j = 0; j < 4; ++j) {
        const float inv = 1.0f / l[j];
        bf16* dst = ctx + (size_t)(q0b + w * 16 + lg * 4 + j) * DIM + h * HEAD_DIM + lr;
#pragma unroll
        for (int d2 = 0; d2 < 8; ++d2)
            dst[d2 * 16] = __float2bfloat16(o[d2][j] * inv);
    }
}

// ---------------- host ----------------
extern "C" void kernel_launch(void* const* d_in, const int* in_sizes, int n_in,
                              void* d_out, int out_size, void* d_ws, size_t ws_size,
                              hipStream_t stream)
{
    const float* x   = (const float*)d_in[0];
    const float* fc  = (const float*)d_in[1];
    const float* fs  = (const float*)d_in[2];
    // d_in[3] = mask (unused; causal computed analytically)
    const float* wq  = (const float*)d_in[4];
    const float* wk  = (const float*)d_in[5];
    const float* wv  = (const float*)d_in[6];
    const float* wo  = (const float*)d_in[7];
    const float* w1  = (const float*)d_in[8];
    const float* w2  = (const float*)d_in[9];
    const float* w3  = (const float*)d_in[10];
    const float* anw = (const float*)d_in[11];
    const float* fnw = (const float*)d_in[12];
    float* out = (float*)d_out;

    char* p = (char*)d_ws;
    auto alloc = [&](size_t n) { char* r = p; p += (n + 255) & ~(size_t)255; return r; };
    bf16* wT  = (bf16*)alloc((size_t)HID * DIM * 2);     // reused per weight group
    bf16* hn  = (bf16*)alloc((size_t)SEQ * DIM * 2);
    bf16* qkv = (bf16*)alloc((size_t)SEQ * SQKV * 2);    // fused q|k|v, stride 6144
    bf16* vt  = (bf16*)alloc((size_t)SEQ * DIM * 2);
    bf16* ctx = (bf16*)alloc((size_t)SEQ * DIM * 2);
    bf16* fn  = (bf16*)alloc((size_t)SEQ * DIM * 2);
    float* h  = (float*)alloc((size_t)SEQ * DIM * 4);
    bf16* g   = (bf16*)alloc((size_t)SEQ * HID * 2);
    float* sk = (float*)alloc((size_t)4 * SEQ * DIM * 4);  // split-K partials (64MB)

    const dim3 tb32(32, 8);
    const int LDS256 = 131072;
    (void)hipFuncSetAttribute((const void*)gemm256_k<0>,
        hipFuncAttributeMaxDynamicSharedMemorySize, LDS256);
    (void)hipFuncSetAttribute((const void*)gemm256_k<2>,
        hipFuncAttributeMaxDynamicSharedMemorySize, LDS256);
    (void)hipFuncSetAttribute((const void*)gemm256_k<3>,
        hipFuncAttributeMaxDynamicSharedMemorySize, LDS256);

    rmsnorm_bf16_k<<<SEQ, 256, 0, stream>>>(x, anw, hn);

    // fused QKV: wT = [wq^T; wk^T; wv^T] (6144x2048) -> qkv[2048][6144]
    convT3_f32_bf16_k<<<dim3(DIM / 32, DIM / 32, 3), tb32, 0, stream>>>(wq, wk, wv, wT);
    gemm256_k<0><<<(SEQ / 256) * (SQKV / 256), 512, LDS256, stream>>>(
        hn, wT, qkv, nullptr, nullptr, SEQ, SQKV, DIM, SQKV / 256, (SEQ / 256) * (SQKV / 256), DIM);

    rope_qk_k<<<(SEQ * 1024) / 256, 256, 0, stream>>>(qkv, qkv + DIM, fc, fs);
    transpose_bf16_k<<<dim3(DIM / 32, SEQ / 32), tb32, 0, stream>>>(qkv + 2 * DIM, SQKV, vt);

    attn_fwd_k<<<dim3(SEQ / 64, N_HEADS), 256, 0, stream>>>(qkv, vt, ctx);

    // h = x + ctx @ wo : split-K=4 (Ks=512) -> partials, fused reduce+residual+rmsnorm
    convT_f32_bf16_k<<<dim3(DIM / 32, DIM / 32), tb32, 0, stream>>>(wo, wT, DIM, DIM);
    gemm256_k<3><<<(SEQ / 256) * (DIM / 256) * 4, 512, LDS256, stream>>>(
        ctx, wT, nullptr, nullptr, sk, SEQ, DIM, DIM, DIM / 256, (SEQ / 256) * (DIM / 256), 512);
    rmsnorm4_k<<<SEQ, 256, 0, stream>>>(sk, x, fnw, h, fn);

    convT_f32_bf16_k<<<dim3(HID / 32, DIM / 32), tb32, 0, stream>>>(w1, wT, DIM, HID);
    gemm256_k<0><<<(SEQ / 256) * (HID / 256), 512, LDS256, stream>>>(
        fn, wT, g, nullptr, nullptr, SEQ, HID, DIM, HID / 256, (SEQ / 256) * (HID / 256), DIM);
    convT_f32_bf16_k<<<dim3(HID / 32, DIM / 32), tb32, 0, stream>>>(w3, wT, DIM, HID);
    gemm256_k<2><<<(SEQ / 256) * (HID / 256), 512, LDS256, stream>>>(
        fn, wT, g, g, nullptr, SEQ, HID, DIM, HID / 256, (SEQ / 256) * (HID / 256), DIM);

    // out = h + g @ w2 : split-K=4 (Ks=2048) -> partials, reduce+residual
    convT_f32_bf16_k<<<dim3(DIM / 32, HID / 32), tb32, 0, stream>>>(w2, wT, HID, DIM);
    gemm256_k<3><<<(SEQ / 256) * (DIM / 256) * 4, 512, LDS256, stream>>>(
        g, wT, nullptr, nullptr, sk, SEQ, DIM, HID, DIM / 256, (SEQ / 256) * (DIM / 256), 2048);
    reduce4_k<<<(SEQ * DIM / 4) / 256, 256, 0, stream>>>(sk, h, out);
}

// Round 12
// 491.381 us; speedup vs baseline: 1.0567x; 1.0385x over previous
//
#include <hip/hip_runtime.h>
#include <hip/hip_bf16.h>

#define DIM 2048
#define HEAD_DIM 128
#define N_HEADS 16
#define SEQ 2048
#define HID 8192
#define SQKV 6144   // row stride of fused qkv activation

typedef short bf16x8 __attribute__((ext_vector_type(8)));
typedef float f32x4 __attribute__((ext_vector_type(4)));
using bf16 = __hip_bfloat16;

#define MFMA16(a, b, c) __builtin_amdgcn_mfma_f32_16x16x32_bf16(a, b, c, 0, 0, 0)

__device__ __forceinline__ unsigned short f2bu(float f) {
    union { bf16 b; unsigned short u; } cv;
    cv.b = __float2bfloat16(f);
    return cv.u;
}

// async global -> LDS, 16B per lane (dest must be lane-linear per wave)
__device__ __forceinline__ void gl16(const void* g, void* l) {
    __builtin_amdgcn_global_load_lds(
        (const __attribute__((address_space(1))) unsigned int*)g,
        (__attribute__((address_space(3))) unsigned int*)l, 16, 0, 0);
}

// ---------------- rmsnorm (fp32 in -> bf16 out) ----------------
__global__ __launch_bounds__(256) void rmsnorm_bf16_k(
    const float* __restrict__ x, const float* __restrict__ w, bf16* __restrict__ y)
{
    const int row = blockIdx.x;
    const int tid = threadIdx.x;
    const float* xr = x + (size_t)row * DIM;
    float4 v0 = ((const float4*)xr)[tid];
    float4 v1 = ((const float4*)xr)[tid + 256];
    float ss = v0.x*v0.x + v0.y*v0.y + v0.z*v0.z + v0.w*v0.w
             + v1.x*v1.x + v1.y*v1.y + v1.z*v1.z + v1.w*v1.w;
    for (int o = 32; o > 0; o >>= 1) ss += __shfl_down(ss, o);
    __shared__ float red[4];
    if ((tid & 63) == 0) red[tid >> 6] = ss;
    __syncthreads();
    float tot = red[0] + red[1] + red[2] + red[3];
    float r = rsqrtf(tot * (1.0f / DIM) + 1e-6f);
    float4 w0 = ((const float4*)w)[tid];
    float4 w1 = ((const float4*)w)[tid + 256];
    ushort4 o0, o1;
    o0.x = f2bu(v0.x * r * w0.x); o0.y = f2bu(v0.y * r * w0.y);
    o0.z = f2bu(v0.z * r * w0.z); o0.w = f2bu(v0.w * r * w0.w);
    o1.x = f2bu(v1.x * r * w1.x); o1.y = f2bu(v1.y * r * w1.y);
    o1.z = f2bu(v1.z * r * w1.z); o1.w = f2bu(v1.w * r * w1.w);
    ushort4* yr = (ushort4*)(y + (size_t)row * DIM);
    yr[tid] = o0;
    yr[tid + 256] = o1;
}

// ---------------- split-K reduce + residual + rmsnorm (fp32 h out, bf16 fn out) ----------------
__global__ __launch_bounds__(256) void rmsnorm4_k(
    const float* __restrict__ part, const float* __restrict__ x,
    const float* __restrict__ w, float* __restrict__ hout, bf16* __restrict__ y)
{
    const int row = blockIdx.x;
    const int tid = threadIdx.x;
    const size_t base = (size_t)row * DIM;
    const size_t SP = (size_t)SEQ * DIM;
    float4 r0, r1;
    float ss = 0.0f;
    {
        float4 a  = ((const float4*)(x + base))[tid];
        float4 p0 = ((const float4*)(part + base))[tid];
        float4 p1 = ((const float4*)(part + SP + base))[tid];
        float4 p2 = ((const float4*)(part + 2 * SP + base))[tid];
        float4 p3 = ((const float4*)(part + 3 * SP + base))[tid];
        r0.x = a.x + ((p0.x + p1.x) + (p2.x + p3.x));
        r0.y = a.y + ((p0.y + p1.y) + (p2.y + p3.y));
        r0.z = a.z + ((p0.z + p1.z) + (p2.z + p3.z));
        r0.w = a.w + ((p0.w + p1.w) + (p2.w + p3.w));
        ((float4*)(hout + base))[tid] = r0;
        ss += r0.x*r0.x + r0.y*r0.y + r0.z*r0.z + r0.w*r0.w;
    }
    {
        const int t2 = tid + 256;
        float4 a  = ((const float4*)(x + base))[t2];
        float4 p0 = ((const float4*)(part + base))[t2];
        float4 p1 = ((const float4*)(part + SP + base))[t2];
        float4 p2 = ((const float4*)(part + 2 * SP + base))[t2];
        float4 p3 = ((const float4*)(part + 3 * SP + base))[t2];
        r1.x = a.x + ((p0.x + p1.x) + (p2.x + p3.x));
        r1.y = a.y + ((p0.y + p1.y) + (p2.y + p3.y));
        r1.z = a.z + ((p0.z + p1.z) + (p2.z + p3.z));
        r1.w = a.w + ((p0.w + p1.w) + (p2.w + p3.w));
        ((float4*)(hout + base))[t2] = r1;
        ss += r1.x*r1.x + r1.y*r1.y + r1.z*r1.z + r1.w*r1.w;
    }
    for (int o = 32; o > 0; o >>= 1) ss += __shfl_down(ss, o);
    __shared__ float red[4];
    if ((tid & 63) == 0) red[tid >> 6] = ss;
    __syncthreads();
    float tot = red[0] + red[1] + red[2] + red[3];
    float r = rsqrtf(tot * (1.0f / DIM) + 1e-6f);
    float4 w0 = ((const float4*)w)[tid];
    float4 w1 = ((const float4*)w)[tid + 256];
    ushort4 o0, o1;
    o0.x = f2bu(r0.x * r * w0.x); o0.y = f2bu(r0.y * r * w0.y);
    o0.z = f2bu(r0.z * r * w0.z); o0.w = f2bu(r0.w * r * w0.w);
    o1.x = f2bu(r1.x * r * w1.x); o1.y = f2bu(r1.y * r * w1.y);
    o1.z = f2bu(r1.z * r * w1.z); o1.w = f2bu(r1.w * r * w1.w);
    ushort4* yr = (ushort4*)(y + base);
    yr[tid] = o0;
    yr[tid + 256] = o1;
}

// ---------------- split-K reduce + residual (fp32 out) ----------------
__global__ __launch_bounds__(256) void reduce4_k(
    const float* __restrict__ part, const float* __restrict__ h, float* __restrict__ out)
{
    const size_t i = (size_t)blockIdx.x * 256 + threadIdx.x;   // float4 index
    const size_t SP4 = (size_t)SEQ * DIM / 4;
    float4 a  = ((const float4*)h)[i];
    float4 p0 = ((const float4*)part)[i];
    float4 p1 = ((const float4*)part)[i + SP4];
    float4 p2 = ((const float4*)part)[i + 2 * SP4];
    float4 p3 = ((const float4*)part)[i + 3 * SP4];
    float4 r;
    r.x = a.x + ((p0.x + p1.x) + (p2.x + p3.x));
    r.y = a.y + ((p0.y + p1.y) + (p2.y + p3.y));
    r.z = a.z + ((p0.z + p1.z) + (p2.z + p3.z));
    r.w = a.w + ((p0.w + p1.w) + (p2.w + p3.w));
    ((float4*)out)[i] = r;
}

// ---------------- fp32 [R][C] -> bf16 [C][R] transpose-convert ----------------
__global__ __launch_bounds__(256) void convT_f32_bf16_k(
    const float* __restrict__ in, bf16* __restrict__ out, int R, int C)
{
    __shared__ float t[32][33];
    const int tx = threadIdx.x, ty = threadIdx.y;
    const int x0 = blockIdx.x * 32, y0 = blockIdx.y * 32;
#pragma unroll
    for (int i = 0; i < 4; ++i)
        t[ty + i * 8][tx] = in[(size_t)(y0 + ty + i * 8) * C + x0 + tx];
    __syncthreads();
#pragma unroll
    for (int i = 0; i < 4; ++i)
        out[(size_t)(x0 + ty + i * 8) * R + y0 + tx] = __float2bfloat16(t[tx][ty + i * 8]);
}

// 3 square weights -> one [3*DIM][DIM] B^T buffer (z selects wq/wk/wv)
__global__ __launch_bounds__(256) void convT3_f32_bf16_k(
    const float* __restrict__ wq, const float* __restrict__ wk,
    const float* __restrict__ wv, bf16* __restrict__ out)
{
    const int z = blockIdx.z;
    const float* in = z == 0 ? wq : (z == 1 ? wk : wv);
    bf16* o = out + (size_t)z * DIM * DIM;
    __shared__ float t[32][33];
    const int tx = threadIdx.x, ty = threadIdx.y;
    const int x0 = blockIdx.x * 32, y0 = blockIdx.y * 32;
#pragma unroll
    for (int i = 0; i < 4; ++i)
        t[ty + i * 8][tx] = in[(size_t)(y0 + ty + i * 8) * DIM + x0 + tx];
    __syncthreads();
#pragma unroll
    for (int i = 0; i < 4; ++i)
        o[(size_t)(x0 + ty + i * 8) * DIM + y0 + tx] = __float2bfloat16(t[tx][ty + i * 8]);
}

// ---------------- bf16 transpose with src stride (vt[d][s] = in[s][d]) ----------------
__global__ __launch_bounds__(256) void transpose_bf16_k(
    const bf16* __restrict__ in, int istride, bf16* __restrict__ out)
{
    __shared__ unsigned short t[32][33];
    const int tx = threadIdx.x, ty = threadIdx.y;
    const int x = blockIdx.x * 32 + tx;       // d
    const int y0 = blockIdx.y * 32;           // s
    const unsigned short* inu = (const unsigned short*)in;
    unsigned short* outu = (unsigned short*)out;
#pragma unroll
    for (int i = 0; i < 4; ++i)
        t[ty + i * 8][tx] = inu[(size_t)(y0 + ty + i * 8) * istride + x];
    __syncthreads();
    const int x2 = blockIdx.y * 32 + tx;
    const int y2 = blockIdx.x * 32;
#pragma unroll
    for (int i = 0; i < 4; ++i)
        outu[(size_t)(y2 + ty + i * 8) * SEQ + x2] = t[tx][ty + i * 8];
}

// ---------------- RoPE in-place on strided bf16 q,k ----------------
__global__ __launch_bounds__(256) void rope_qk_k(
    bf16* __restrict__ q, bf16* __restrict__ k,
    const float* __restrict__ cosb, const float* __restrict__ sinb)
{
    const int gid = blockIdx.x * 256 + threadIdx.x;   // < SEQ * 1024
    const int s = gid >> 10;
    const int p = gid & 1023;
    const int h = p >> 6, j = p & 63;
    const size_t off = (size_t)s * SQKV + h * HEAD_DIM + 2 * j;
    const float c = cosb[s * 64 + j], sn = sinb[s * 64 + j];
    float xr = __bfloat162float(q[off]), xi = __bfloat162float(q[off + 1]);
    q[off]     = __float2bfloat16(xr * c - xi * sn);
    q[off + 1] = __float2bfloat16(xr * sn + xi * c);
    xr = __bfloat162float(k[off]); xi = __bfloat162float(k[off + 1]);
    k[off]     = __float2bfloat16(xr * c - xi * sn);
    k[off + 1] = __float2bfloat16(xr * sn + xi * c);
}

// ---------------- 256x256 GEMM, m201 8-phase skeleton, BK=64 x2/iter, split-K ----------------
// EP 0: store bf16    EP 3: fp32 partial store
// EP 4: fused w1|w3 -> silu(w1part)*w3part (B rows interleaved per-16 from Bt/Bt2;
//       acc[mf][nf] pairs (nf,nf+1) = same HID col in same lane; out stride N/2)
// LDS (dynamic 128KB): A halves [buf][half][128x64] at (buf*2+half)*16KB; B at +64KB.
// Swizzle byte^=((row&7)<<4); inverse pre-applied on global src of gl16 (rule #21).
// T5 setprio around MFMA clusters (m218b: +21-25% on 8-phase+swz).
template <int EP>
__global__ __launch_bounds__(512, 1) void gemm256_k(
    const bf16* __restrict__ A, const bf16* __restrict__ Bt, const bf16* __restrict__ Bt2,
    bf16* __restrict__ Cb, float* __restrict__ Pf,
    int M, int N, int K, int gx, int ntile, int Ks)
{
    extern __shared__ char smem[];
    const int t512 = threadIdx.x;
    const int w = t512 >> 6, lane = t512 & 63;
    const int lr = lane & 15, lg = lane >> 4;
    const int wm = w >> 2, wn = w & 3;           // 2 x 4 wave grid
    const int bofs = (wn & 1) * 64;              // B row offset inside its half
    const int swz = (lr & 7) << 4;               // ds_read swizzle

    // XCD-bijective block swizzle (m204)
    const int nwg = gridDim.x;                    // = ntile * splitk
    const int q8 = nwg >> 3, r8 = nwg & 7;
    const int xcd = blockIdx.x & 7, seqq = blockIdx.x >> 3;
    const int wgid = (xcd < r8 ? xcd * (q8 + 1) : r8 * (q8 + 1) + (xcd - r8) * q8) + seqq;
    const int split = wgid / ntile;
    const int tile = wgid % ntile;
    // GROUP_M=4 supertiling (M/256 divisible by 4 for all uses)
    const int grp = tile / (4 * gx), rem = tile % (4 * gx);
    const int m0 = (grp * 4 + (rem & 3)) * 256, n0 = (rem >> 2) * 256;
    const int kb0 = split * Ks;
    const int niter = Ks >> 7;                    // 2 K-tiles per iteration (Ks % 128 == 0)

    // staging source pointers (pre-swizzled), advance by kt*64 elements
    const bf16* aS[2][2]; const bf16* bS[2][2];   // [half][c]
    int sOff[2];
#pragma unroll
    for (int c = 0; c < 2; ++c) {
        const int s = (c * 512 + t512) * 16;            // linear byte slot
        const int pp = s ^ (((s >> 7) & 7) << 4);       // nominal position (involution)
        const int row = pp >> 7, colE = (pp & 127) >> 1;
        sOff[c] = s;
#pragma unroll
        for (int hs = 0; hs < 2; ++hs) {
            aS[hs][c] = A + (size_t)(m0 + hs * 128 + row) * K + kb0 + colE;
            const int rg = n0 + hs * 128 + row;
            if (EP == 4) {
                const int g = rg >> 4;
                const bf16* src = (g & 1) ? Bt2 : Bt;
                const int j = ((g >> 1) << 4) + (rg & 15);
                bS[hs][c] = src + (size_t)j * K + kb0 + colE;
            } else {
                bS[hs][c] = Bt + (size_t)rg * K + kb0 + colE;
            }
        }
    }
    auto stA = [&](int buf, int kt, int hs) {      // one A half-tile: 2 gl16/thread
        char* base = smem + (buf * 2 + hs) * 16384;
        gl16(aS[hs][0] + (kt << 6), base + sOff[0]);
        gl16(aS[hs][1] + (kt << 6), base + sOff[1]);
    };
    auto stB = [&](int buf, int kt, int hs) {      // one B half-tile
        char* base = smem + 65536 + (buf * 2 + hs) * 16384;
        gl16(bS[hs][0] + (kt << 6), base + sOff[0]);
        gl16(bS[hs][1] + (kt << 6), base + sOff[1]);
    };

    // per-wave LDS read bases (loop-invariant)
    const char* A0m = smem + (0 * 2 + wm) * 16384;
    const char* A1m = smem + (1 * 2 + wm) * 16384;
    const char* B0m = smem + 65536 + (0 * 2 + (wn >> 1)) * 16384;
    const char* B1m = smem + 65536 + (1 * 2 + (wn >> 1)) * 16384;

    f32x4 acc[8][4] = {};
    bf16x8 bfr[4][2];
    bf16x8 x0, x1, x2, x3;

#define SBAR __builtin_amdgcn_s_barrier()
#define LGKM0 do { asm volatile("s_waitcnt lgkmcnt(0)" ::: "memory"); \
                   __builtin_amdgcn_sched_barrier(0); } while (0)
#define WVM(n) do { asm volatile("s_waitcnt vmcnt(" #n ")" ::: "memory"); \
                    __builtin_amdgcn_sched_barrier(0); } while (0)
#define LDA4(base, mf0) do { \
    x0 = *(const bf16x8*)((base) + (((mf0) * 16 + lr) * 128) + ((lg * 16) ^ swz)); \
    x1 = *(const bf16x8*)((base) + (((mf0) * 16 + lr) * 128) + ((64 + lg * 16) ^ swz)); \
    x2 = *(const bf16x8*)((base) + ((((mf0) + 1) * 16 + lr) * 128) + ((lg * 16) ^ swz)); \
    x3 = *(const bf16x8*)((base) + ((((mf0) + 1) * 16 + lr) * 128) + ((64 + lg * 16) ^ swz)); \
    } while (0)
#define LDB8(base) do { \
    _Pragma("unroll") \
    for (int nf = 0; nf < 4; ++nf) { \
        bfr[nf][0] = *(const bf16x8*)((base) + ((bofs + nf * 16 + lr) * 128) + ((lg * 16) ^ swz)); \
        bfr[nf][1] = *(const bf16x8*)((base) + ((bofs + nf * 16 + lr) * 128) + ((64 + lg * 16) ^ swz)); \
    } } while (0)
#define MFMA_PH(mf0) do { \
    __builtin_amdgcn_s_setprio(1); \
    _Pragma("unroll") \
    for (int nf = 0; nf < 4; ++nf) { \
        acc[(mf0)][nf]     = MFMA16(x0, bfr[nf][0], acc[(mf0)][nf]); \
        acc[(mf0)][nf]     = MFMA16(x1, bfr[nf][1], acc[(mf0)][nf]); \
        acc[(mf0) + 1][nf] = MFMA16(x2, bfr[nf][0], acc[(mf0) + 1][nf]); \
        acc[(mf0) + 1][nf] = MFMA16(x3, bfr[nf][1], acc[(mf0) + 1][nf]); \
    } \
    __builtin_amdgcn_s_setprio(0); } while (0)

    // prologue: tile0 B+A (8 gl16), tile1 B (4 gl16); tile1 A staged in iter0 ph1/ph2
    stB(0, 0, 0); stB(0, 0, 1); stA(0, 0, 0); stA(0, 0, 1);
    stB(1, 1, 0); stB(1, 1, 1);
    WVM(4);                 // tile0's 8 landed; tile1-B still in flight
    SBAR;                   // publish

    for (int t = 0; t < niter; ++t) {
        const bool pf = (t + 1 < niter);
        const int k1 = 2 * t + 1, k2 = 2 * t + 2, k3 = 2 * t + 3;

        // ---- ph1: K-tile 2t quadrant 0 (+ stage A of buf1) ----
        LDB8(B0m);
        LDA4(A0m, 0);
        stA(1, k1, 0);
        SBAR; LGKM0; MFMA_PH(0); SBAR;
        // ---- ph2 ----
        LDA4(A0m, 2);
        stA(1, k1, 1);
        SBAR; LGKM0; MFMA_PH(2); SBAR;
        // ---- ph3 ----
        LDA4(A0m, 4);
        if (pf) stB(0, k2, 0);
        SBAR; LGKM0; MFMA_PH(4); SBAR;
        // ---- ph4: wait covers {prev B1 halves, this A1 halves} for ph5-8 ----
        if (pf) { WVM(2); } else { WVM(0); }
        LDA4(A0m, 6);
        if (pf) stB(0, k2, 1);
        SBAR; LGKM0; MFMA_PH(6); SBAR;
        // ---- ph5: K-tile 2t+1 quadrant 0 (+ stage A of buf0) ----
        LDB8(B1m);
        LDA4(A1m, 0);
        if (pf) stA(0, k2, 0);
        SBAR; LGKM0; MFMA_PH(0); SBAR;
        // ---- ph6 ----
        LDA4(A1m, 2);
        if (pf) stA(0, k2, 1);
        SBAR; LGKM0; MFMA_PH(2); SBAR;
        // ---- ph7 ----
        LDA4(A1m, 4);
        if (pf) stB(1, k3, 0);
        SBAR; LGKM0; MFMA_PH(4); SBAR;
        // ---- ph8: wait covers {this B0',A0'} for next ph1 ----
        if (pf) WVM(2);
        LDA4(A1m, 6);
        if (pf) stB(1, k3, 1);
        SBAR; LGKM0; MFMA_PH(6); SBAR;
    }
#undef SBAR
#undef LGKM0
#undef WVM
#undef LDA4
#undef LDB8
#undef MFMA_PH

    // ---- epilogue ----
    if (EP == 4) {
        // pairs (nf, nf+1) = (w1, w3) products of the same HID column, same lane
        const int jb = (n0 >> 1) + wn * 32;
        const int NH = N >> 1;                  // = HID
#pragma unroll
        for (int mf = 0; mf < 8; ++mf)
#pragma unroll
            for (int pp = 0; pp < 4; pp += 2) {
                const int row = m0 + wm * 128 + mf * 16 + lg * 4;
                const int j = jb + (pp >> 1) * 16 + lr;
#pragma unroll
                for (int r = 0; r < 4; ++r) {
                    const float a = acc[mf][pp][r];
                    const float b = acc[mf][pp + 1][r];
                    const float s = a / (1.0f + __expf(-a));
                    Cb[(size_t)(row + r) * NH + j] = __float2bfloat16(s * b);
                }
            }
    } else {
        float* pf_base = Pf + (size_t)split * M * N;
#pragma unroll
        for (int mf = 0; mf < 8; ++mf)
#pragma unroll
            for (int nf = 0; nf < 4; ++nf) {
                const int row = m0 + wm * 128 + mf * 16 + lg * 4;
                const int col = n0 + wn * 64 + nf * 16 + lr;
#pragma unroll
                for (int r = 0; r < 4; ++r) {
                    const size_t idx = (size_t)(row + r) * N + col;
                    const float v = acc[mf][nf][r];
                    if (EP == 0) Cb[idx] = __float2bfloat16(v);
                    else         pf_base[idx] = v;
                }
            }
    }
}

// ---------------- causal flash attention: QBLK=64 (4 waves x 16 rows), shared KV tiles ----------------
__global__ __launch_bounds__(256) void attn_fwd_k(
    const bf16* __restrict__ qkv, const bf16* __restrict__ vT, bf16* __restrict__ ctx)
{
    const int tid = threadIdx.x;
    const int w = tid >> 6, lane = tid & 63;
    const int lr = lane & 15, lg = lane >> 4;
    const int h = blockIdx.y;
    const int qidx = (blockIdx.y < 8) ? blockIdx.x : (31 - blockIdx.x);
    const int q0b = qidx * 64;
    const int nt = qidx + 1;                  // 64-row KV tiles (causal)

    __shared__ __align__(16) unsigned short Kt[2][64 * 128];
    __shared__ __align__(16) unsigned short Vt[2][128 * 64];
    __shared__ __align__(16) unsigned short Pp[4][16 * 64];

    const char* kbase = (const char*)(qkv + DIM + h * HEAD_DIM);
    const char* vbase = (const char*)(vT + (size_t)h * HEAD_DIM * SEQ);

    const int krow_c = tid >> 4;
    const int kcolB  = (tid & 15) * 16;
    const int vrow_c = tid >> 3;
    const int vcolB  = (tid & 7) * 16;

    auto stage = [&](int buf, int kb) {
#pragma unroll
        for (int c = 0; c < 4; ++c) {
            const int r = c * 16 + krow_c;
            gl16(kbase + (size_t)(kb + r) * (SQKV * 2) + (kcolB ^ ((r & 7) << 4)),
                 &Kt[buf][c * 2048 + tid * 8]);
        }
#pragma unroll
        for (int c = 0; c < 4; ++c) {
            const int r = c * 32 + vrow_c;
            gl16(vbase + (size_t)r * (SEQ * 2) + kb * 2 + (vcolB ^ ((r & 7) << 4)),
                 &Vt[buf][c * 2048 + tid * 8]);
        }
    };

    bf16x8 qf[4];
    const bf16* qrow = qkv + (size_t)(q0b + w * 16 + lr) * SQKV + h * HEAD_DIM;
#pragma unroll
    for (int dt = 0; dt < 4; ++dt)
        qf[dt] = *(const bf16x8*)(qrow + dt * 32 + lg * 8);

    f32x4 o[8] = {};
    float m[4], l[4];
#pragma unroll
    for (int j = 0; j < 4; ++j) { m[j] = -3e38f; l[j] = 0.0f; }
    const float scale = 0.08838834764831845f;

    stage(0, 0);
    __syncthreads();

    int cur = 0;
    for (int t = 0; t < nt; ++t) {
        const int kb = t * 64;
        if (t + 1 < nt) stage(cur ^ 1, kb + 64);

        f32x4 s[4] = {};
        __builtin_amdgcn_s_setprio(1);
#pragma unroll
        for (int ss = 0; ss < 4; ++ss) {
            const int r = ss * 16 + lr;
            const int sw = (r & 7) << 3;
#pragma unroll
            for (int dt = 0; dt < 4; ++dt) {
                bf16x8 kf = *(const bf16x8*)&Kt[cur][r * 128 + ((dt * 32 + lg * 8) ^ sw)];
                s[ss] = MFMA16(qf[dt], kf, s[ss]);
            }
        }
        __builtin_amdgcn_s_setprio(0);

        float al[4];
#pragma unroll
        for (int j = 0; j < 4; ++j) {
            const int qi = q0b + w * 16 + lg * 4 + j;
            const int prow = lg * 4 + j;
            const int psw = (prow & 7) << 3;
            float a[4];
#pragma unroll
            for (int ss = 0; ss < 4; ++ss)
                a[ss] = s[ss][j] * scale + ((kb + ss * 16 + lr) > qi ? -1e9f : 0.0f);
            float mx = fmaxf(fmaxf(a[0], a[1]), fmaxf(a[2], a[3]));
            mx = fmaxf(mx, __shfl_xor(mx, 1));
            mx = fmaxf(mx, __shfl_xor(mx, 2));
            mx = fmaxf(mx, __shfl_xor(mx, 4));
            mx = fmaxf(mx, __shfl_xor(mx, 8));
            const float mn = fmaxf(m[j], mx);
            const float asc = __expf(m[j] - mn);
            float e0 = __expf(a[0] - mn), e1 = __expf(a[1] - mn);
            float e2 = __expf(a[2] - mn), e3 = __expf(a[3] - mn);
            float rs = (e0 + e1) + (e2 + e3);
            rs += __shfl_xor(rs, 1); rs += __shfl_xor(rs, 2);
            rs += __shfl_xor(rs, 4); rs += __shfl_xor(rs, 8);
            l[j] = l[j] * asc + rs;
            m[j] = mn;
            al[j] = asc;
            Pp[w][prow * 64 + ((lr)      ^ psw)] = f2bu(e0);
            Pp[w][prow * 64 + ((16 + lr) ^ psw)] = f2bu(e1);
            Pp[w][prow * 64 + ((32 + lr) ^ psw)] = f2bu(e2);
            Pp[w][prow * 64 + ((48 + lr) ^ psw)] = f2bu(e3);
        }
#pragma unroll
        for (int d2 = 0; d2 < 8; ++d2)
#pragma unroll
            for (int j = 0; j < 4; ++j) o[d2][j] *= al[j];

        asm volatile("s_waitcnt lgkmcnt(0)" ::: "memory");
        __builtin_amdgcn_sched_barrier(0);
        const int asw = (lr & 7) << 3;
        bf16x8 pa0 = *(const bf16x8*)&Pp[w][lr * 64 + ((lg * 8)      ^ asw)];
        bf16x8 pa1 = *(const bf16x8*)&Pp[w][lr * 64 + ((32 + lg * 8) ^ asw)];

        __builtin_amdgcn_s_setprio(1);
#pragma unroll
        for (int d2 = 0; d2 < 8; ++d2) {
            const int rv = d2 * 16 + lr;
            const int vsw = (rv & 7) << 3;
            bf16x8 vf0 = *(const bf16x8*)&Vt[cur][rv * 64 + ((lg * 8)      ^ vsw)];
            bf16x8 vf1 = *(const bf16x8*)&Vt[cur][rv * 64 + ((32 + lg * 8) ^ vsw)];
            o[d2] = MFMA16(pa0, vf0, o[d2]);
            o[d2] = MFMA16(pa1, vf1, o[d2]);
        }
        __builtin_amdgcn_s_setprio(0);

        __syncthreads();
        cur ^= 1;
    }

#pragma unroll
    for (int j = 0; j < 4; ++j) {
        const float inv = 1.0f / l[j];
        bf16* dst = ctx + (size_t)(q0b + w * 16 + lg * 4 + j) * DIM + h * HEAD_DIM + lr;
#pragma unroll
        for (int d2 = 0; d2 < 8; ++d2)
            dst[d2 * 16] = __float2bfloat16(o[d2][j] * inv);
    }
}

// ---------------- host ----------------
extern "C" void kernel_launch(void* const* d_in, const int* in_sizes, int n_in,
                              void* d_out, int out_size, void* d_ws, size_t ws_size,
                              hipStream_t stream)
{
    const float* x   = (const float*)d_in[0];
    const float* fc  = (const float*)d_in[1];
    const float* fs  = (const float*)d_in[2];
    // d_in[3] = mask (unused; causal computed analytically)
    const float* wq  = (const float*)d_in[4];
    const float* wk  = (const float*)d_in[5];
    const float* wv  = (const float*)d_in[6];
    const float* wo  = (const float*)d_in[7];
    const float* w1  = (const float*)d_in[8];
    const float* w2  = (const float*)d_in[9];
    const float* w3  = (const float*)d_in[10];
    const float* anw = (const float*)d_in[11];
    const float* fnw = (const float*)d_in[12];
    float* out = (float*)d_out;

    char* p = (char*)d_ws;
    auto alloc = [&](size_t n) { char* r = p; p += (n + 255) & ~(size_t)255; return r; };
    bf16* wT  = (bf16*)alloc((size_t)HID * DIM * 2);     // reused per weight group
    bf16* hn  = (bf16*)alloc((size_t)SEQ * DIM * 2);     // dead after QKV GEMM
    bf16* qkv = (bf16*)alloc((size_t)SEQ * SQKV * 2);    // dead after attn
    bf16* vt  = (bf16*)alloc((size_t)SEQ * DIM * 2);
    bf16* ctx = (bf16*)alloc((size_t)SEQ * DIM * 2);
    bf16* fn  = (bf16*)alloc((size_t)SEQ * DIM * 2);
    float* h  = (float*)alloc((size_t)SEQ * DIM * 4);
    bf16* g   = (bf16*)alloc((size_t)SEQ * HID * 2);
    float* sk = (float*)alloc((size_t)4 * SEQ * DIM * 4);  // split-K partials (64MB)
    // w3^T aliases hn+qkv (both dead by the time it's written): 8192*2048*2 = 33,554,432 B
    // = exactly sizeof(hn)+sizeof(qkv).
    bf16* w3T = hn;

    const dim3 tb32(32, 8);
    const int LDS256 = 131072;
    (void)hipFuncSetAttribute((const void*)gemm256_k<0>,
        hipFuncAttributeMaxDynamicSharedMemorySize, LDS256);
    (void)hipFuncSetAttribute((const void*)gemm256_k<3>,
        hipFuncAttributeMaxDynamicSharedMemorySize, LDS256);
    (void)hipFuncSetAttribute((const void*)gemm256_k<4>,
        hipFuncAttributeMaxDynamicSharedMemorySize, LDS256);

    rmsnorm_bf16_k<<<SEQ, 256, 0, stream>>>(x, anw, hn);

    // fused QKV: wT = [wq^T; wk^T; wv^T] (6144x2048) -> qkv[2048][6144]
    convT3_f32_bf16_k<<<dim3(DIM / 32, DIM / 32, 3), tb32, 0, stream>>>(wq, wk, wv, wT);
    gemm256_k<0><<<(SEQ / 256) * (SQKV / 256), 512, LDS256, stream>>>(
        hn, wT, nullptr, qkv, nullptr, SEQ, SQKV, DIM, SQKV / 256, (SEQ / 256) * (SQKV / 256), DIM);

    rope_qk_k<<<(SEQ * 1024) / 256, 256, 0, stream>>>(qkv, qkv + DIM, fc, fs);
    transpose_bf16_k<<<dim3(DIM / 32, SEQ / 32), tb32, 0, stream>>>(qkv + 2 * DIM, SQKV, vt);

    attn_fwd_k<<<dim3(SEQ / 64, N_HEADS), 256, 0, stream>>>(qkv, vt, ctx);

    // h = x + ctx @ wo : split-K=4 (Ks=512) -> partials, fused reduce+residual+rmsnorm
    convT_f32_bf16_k<<<dim3(DIM / 32, DIM / 32), tb32, 0, stream>>>(wo, wT, DIM, DIM);
    gemm256_k<3><<<(SEQ / 256) * (DIM / 256) * 4, 512, LDS256, stream>>>(
        ctx, wT, nullptr, nullptr, sk, SEQ, DIM, DIM, DIM / 256, (SEQ / 256) * (DIM / 256), 512);
    rmsnorm4_k<<<SEQ, 256, 0, stream>>>(sk, x, fnw, h, fn);

    // fused FFN-up: g = silu(fn@w1) * (fn@w3), single GEMM over N'=16384
    convT_f32_bf16_k<<<dim3(HID / 32, DIM / 32), tb32, 0, stream>>>(w1, wT, DIM, HID);
    convT_f32_bf16_k<<<dim3(HID / 32, DIM / 32), tb32, 0, stream>>>(w3, w3T, DIM, HID);
    gemm256_k<4><<<(SEQ / 256) * ((2 * HID) / 256), 512, LDS256, stream>>>(
        fn, wT, w3T, g, nullptr, SEQ, 2 * HID, DIM, (2 * HID) / 256,
        (SEQ / 256) * ((2 * HID) / 256), DIM);

    // out = h + g @ w2 : split-K=4 (Ks=2048) -> partials, reduce+residual
    convT_f32_bf16_k<<<dim3(DIM / 32, HID / 32), tb32, 0, stream>>>(w2, wT, HID, DIM);
    gemm256_k<3><<<(SEQ / 256) * (DIM / 256) * 4, 512, LDS256, stream>>>(
        g, wT, nullptr, nullptr, sk, SEQ, DIM, HID, DIM / 256, (SEQ / 256) * (DIM / 256), 2048);
    reduce4_k<<<(SEQ * DIM / 4) / 256, 256, 0, stream>>>(sk, h, out);
}

// Round 13
// 476.979 us; speedup vs baseline: 1.0886x; 1.0302x over previous
//
#include <hip/hip_runtime.h>
#include <hip/hip_bf16.h>

#define DIM 2048
#define HEAD_DIM 128
#define N_HEADS 16
#define SEQ 2048
#define HID 8192
#define SQKV 6144   // row stride of fused qkv activation

typedef short bf16x8 __attribute__((ext_vector_type(8)));
typedef float f32x4 __attribute__((ext_vector_type(4)));
using bf16 = __hip_bfloat16;

#define MFMA16(a, b, c) __builtin_amdgcn_mfma_f32_16x16x32_bf16(a, b, c, 0, 0, 0)

__device__ __forceinline__ unsigned short f2bu(float f) {
    union { bf16 b; unsigned short u; } cv;
    cv.b = __float2bfloat16(f);
    return cv.u;
}

// async global -> LDS, 16B per lane (dest must be lane-linear per wave)
__device__ __forceinline__ void gl16(const void* g, void* l) {
    __builtin_amdgcn_global_load_lds(
        (const __attribute__((address_space(1))) unsigned int*)g,
        (__attribute__((address_space(3))) unsigned int*)l, 16, 0, 0);
}

// ---------------- rmsnorm (fp32 in -> bf16 out) ----------------
__global__ __launch_bounds__(256) void rmsnorm_bf16_k(
    const float* __restrict__ x, const float* __restrict__ w, bf16* __restrict__ y)
{
    const int row = blockIdx.x;
    const int tid = threadIdx.x;
    const float* xr = x + (size_t)row * DIM;
    float4 v0 = ((const float4*)xr)[tid];
    float4 v1 = ((const float4*)xr)[tid + 256];
    float ss = v0.x*v0.x + v0.y*v0.y + v0.z*v0.z + v0.w*v0.w
             + v1.x*v1.x + v1.y*v1.y + v1.z*v1.z + v1.w*v1.w;
    for (int o = 32; o > 0; o >>= 1) ss += __shfl_down(ss, o);
    __shared__ float red[4];
    if ((tid & 63) == 0) red[tid >> 6] = ss;
    __syncthreads();
    float tot = red[0] + red[1] + red[2] + red[3];
    float r = rsqrtf(tot * (1.0f / DIM) + 1e-6f);
    float4 w0 = ((const float4*)w)[tid];
    float4 w1 = ((const float4*)w)[tid + 256];
    ushort4 o0, o1;
    o0.x = f2bu(v0.x * r * w0.x); o0.y = f2bu(v0.y * r * w0.y);
    o0.z = f2bu(v0.z * r * w0.z); o0.w = f2bu(v0.w * r * w0.w);
    o1.x = f2bu(v1.x * r * w1.x); o1.y = f2bu(v1.y * r * w1.y);
    o1.z = f2bu(v1.z * r * w1.z); o1.w = f2bu(v1.w * r * w1.w);
    ushort4* yr = (ushort4*)(y + (size_t)row * DIM);
    yr[tid] = o0;
    yr[tid + 256] = o1;
}

// ---------------- split-K reduce + residual + rmsnorm (fp32 h out, bf16 fn out) ----------------
__global__ __launch_bounds__(256) void rmsnorm4_k(
    const float* __restrict__ part, const float* __restrict__ x,
    const float* __restrict__ w, float* __restrict__ hout, bf16* __restrict__ y)
{
    const int row = blockIdx.x;
    const int tid = threadIdx.x;
    const size_t base = (size_t)row * DIM;
    const size_t SP = (size_t)SEQ * DIM;
    float4 r0, r1;
    float ss = 0.0f;
    {
        float4 a  = ((const float4*)(x + base))[tid];
        float4 p0 = ((const float4*)(part + base))[tid];
        float4 p1 = ((const float4*)(part + SP + base))[tid];
        float4 p2 = ((const float4*)(part + 2 * SP + base))[tid];
        float4 p3 = ((const float4*)(part + 3 * SP + base))[tid];
        r0.x = a.x + ((p0.x + p1.x) + (p2.x + p3.x));
        r0.y = a.y + ((p0.y + p1.y) + (p2.y + p3.y));
        r0.z = a.z + ((p0.z + p1.z) + (p2.z + p3.z));
        r0.w = a.w + ((p0.w + p1.w) + (p2.w + p3.w));
        ((float4*)(hout + base))[tid] = r0;
        ss += r0.x*r0.x + r0.y*r0.y + r0.z*r0.z + r0.w*r0.w;
    }
    {
        const int t2 = tid + 256;
        float4 a  = ((const float4*)(x + base))[t2];
        float4 p0 = ((const float4*)(part + base))[t2];
        float4 p1 = ((const float4*)(part + SP + base))[t2];
        float4 p2 = ((const float4*)(part + 2 * SP + base))[t2];
        float4 p3 = ((const float4*)(part + 3 * SP + base))[t2];
        r1.x = a.x + ((p0.x + p1.x) + (p2.x + p3.x));
        r1.y = a.y + ((p0.y + p1.y) + (p2.y + p3.y));
        r1.z = a.z + ((p0.z + p1.z) + (p2.z + p3.z));
        r1.w = a.w + ((p0.w + p1.w) + (p2.w + p3.w));
        ((float4*)(hout + base))[t2] = r1;
        ss += r1.x*r1.x + r1.y*r1.y + r1.z*r1.z + r1.w*r1.w;
    }
    for (int o = 32; o > 0; o >>= 1) ss += __shfl_down(ss, o);
    __shared__ float red[4];
    if ((tid & 63) == 0) red[tid >> 6] = ss;
    __syncthreads();
    float tot = red[0] + red[1] + red[2] + red[3];
    float r = rsqrtf(tot * (1.0f / DIM) + 1e-6f);
    float4 w0 = ((const float4*)w)[tid];
    float4 w1 = ((const float4*)w)[tid + 256];
    ushort4 o0, o1;
    o0.x = f2bu(r0.x * r * w0.x); o0.y = f2bu(r0.y * r * w0.y);
    o0.z = f2bu(r0.z * r * w0.z); o0.w = f2bu(r0.w * r * w0.w);
    o1.x = f2bu(r1.x * r * w1.x); o1.y = f2bu(r1.y * r * w1.y);
    o1.z = f2bu(r1.z * r * w1.z); o1.w = f2bu(r1.w * r * w1.w);
    ushort4* yr = (ushort4*)(y + base);
    yr[tid] = o0;
    yr[tid + 256] = o1;
}

// ---------------- split-K reduce + residual (fp32 out) ----------------
__global__ __launch_bounds__(256) void reduce4_k(
    const float* __restrict__ part, const float* __restrict__ h, float* __restrict__ out)
{
    const size_t i = (size_t)blockIdx.x * 256 + threadIdx.x;   // float4 index
    const size_t SP4 = (size_t)SEQ * DIM / 4;
    float4 a  = ((const float4*)h)[i];
    float4 p0 = ((const float4*)part)[i];
    float4 p1 = ((const float4*)part)[i + SP4];
    float4 p2 = ((const float4*)part)[i + 2 * SP4];
    float4 p3 = ((const float4*)part)[i + 3 * SP4];
    float4 r;
    r.x = a.x + ((p0.x + p1.x) + (p2.x + p3.x));
    r.y = a.y + ((p0.y + p1.y) + (p2.y + p3.y));
    r.z = a.z + ((p0.z + p1.z) + (p2.z + p3.z));
    r.w = a.w + ((p0.w + p1.w) + (p2.w + p3.w));
    ((float4*)out)[i] = r;
}

// ---------------- fp32 [R][C] -> bf16 [C][R] transpose-convert ----------------
__global__ __launch_bounds__(256) void convT_f32_bf16_k(
    const float* __restrict__ in, bf16* __restrict__ out, int R, int C)
{
    __shared__ float t[32][33];
    const int tx = threadIdx.x, ty = threadIdx.y;
    const int x0 = blockIdx.x * 32, y0 = blockIdx.y * 32;
#pragma unroll
    for (int i = 0; i < 4; ++i)
        t[ty + i * 8][tx] = in[(size_t)(y0 + ty + i * 8) * C + x0 + tx];
    __syncthreads();
#pragma unroll
    for (int i = 0; i < 4; ++i)
        out[(size_t)(x0 + ty + i * 8) * R + y0 + tx] = __float2bfloat16(t[tx][ty + i * 8]);
}

// 3 square weights -> one [3*DIM][DIM] B^T buffer (z selects wq/wk/wv)
__global__ __launch_bounds__(256) void convT3_f32_bf16_k(
    const float* __restrict__ wq, const float* __restrict__ wk,
    const float* __restrict__ wv, bf16* __restrict__ out)
{
    const int z = blockIdx.z;
    const float* in = z == 0 ? wq : (z == 1 ? wk : wv);
    bf16* o = out + (size_t)z * DIM * DIM;
    __shared__ float t[32][33];
    const int tx = threadIdx.x, ty = threadIdx.y;
    const int x0 = blockIdx.x * 32, y0 = blockIdx.y * 32;
#pragma unroll
    for (int i = 0; i < 4; ++i)
        t[ty + i * 8][tx] = in[(size_t)(y0 + ty + i * 8) * DIM + x0 + tx];
    __syncthreads();
#pragma unroll
    for (int i = 0; i < 4; ++i)
        o[(size_t)(x0 + ty + i * 8) * DIM + y0 + tx] = __float2bfloat16(t[tx][ty + i * 8]);
}

// ---------------- bf16 transpose with src stride (vt[d][s] = in[s][d]) ----------------
__global__ __launch_bounds__(256) void transpose_bf16_k(
    const bf16* __restrict__ in, int istride, bf16* __restrict__ out)
{
    __shared__ unsigned short t[32][33];
    const int tx = threadIdx.x, ty = threadIdx.y;
    const int x = blockIdx.x * 32 + tx;       // d
    const int y0 = blockIdx.y * 32;           // s
    const unsigned short* inu = (const unsigned short*)in;
    unsigned short* outu = (unsigned short*)out;
#pragma unroll
    for (int i = 0; i < 4; ++i)
        t[ty + i * 8][tx] = inu[(size_t)(y0 + ty + i * 8) * istride + x];
    __syncthreads();
    const int x2 = blockIdx.y * 32 + tx;
    const int y2 = blockIdx.x * 32;
#pragma unroll
    for (int i = 0; i < 4; ++i)
        outu[(size_t)(y2 + ty + i * 8) * SEQ + x2] = t[tx][ty + i * 8];
}

// ---------------- RoPE in-place on strided bf16 q,k ----------------
__global__ __launch_bounds__(256) void rope_qk_k(
    bf16* __restrict__ q, bf16* __restrict__ k,
    const float* __restrict__ cosb, const float* __restrict__ sinb)
{
    const int gid = blockIdx.x * 256 + threadIdx.x;   // < SEQ * 1024
    const int s = gid >> 10;
    const int p = gid & 1023;
    const int h = p >> 6, j = p & 63;
    const size_t off = (size_t)s * SQKV + h * HEAD_DIM + 2 * j;
    const float c = cosb[s * 64 + j], sn = sinb[s * 64 + j];
    float xr = __bfloat162float(q[off]), xi = __bfloat162float(q[off + 1]);
    q[off]     = __float2bfloat16(xr * c - xi * sn);
    q[off + 1] = __float2bfloat16(xr * sn + xi * c);
    xr = __bfloat162float(k[off]); xi = __bfloat162float(k[off + 1]);
    k[off]     = __float2bfloat16(xr * c - xi * sn);
    k[off + 1] = __float2bfloat16(xr * sn + xi * c);
}

// ---------------- 256x256 GEMM, m201 8-phase skeleton, BK=64 x2/iter, split-K ----------------
// EP 0: store bf16    EP 3: fp32 partial store
// EP 4: fused w1|w3 -> silu(w1part)*w3part (B rows interleaved per-16 from Bt/Bt2)
template <int EP>
__global__ __launch_bounds__(512, 1) void gemm256_k(
    const bf16* __restrict__ A, const bf16* __restrict__ Bt, const bf16* __restrict__ Bt2,
    bf16* __restrict__ Cb, float* __restrict__ Pf,
    int M, int N, int K, int gx, int ntile, int Ks)
{
    extern __shared__ char smem[];
    const int t512 = threadIdx.x;
    const int w = t512 >> 6, lane = t512 & 63;
    const int lr = lane & 15, lg = lane >> 4;
    const int wm = w >> 2, wn = w & 3;           // 2 x 4 wave grid
    const int bofs = (wn & 1) * 64;              // B row offset inside its half
    const int swz = (lr & 7) << 4;               // ds_read swizzle

    // XCD-bijective block swizzle (m204)
    const int nwg = gridDim.x;                    // = ntile * splitk
    const int q8 = nwg >> 3, r8 = nwg & 7;
    const int xcd = blockIdx.x & 7, seqq = blockIdx.x >> 3;
    const int wgid = (xcd < r8 ? xcd * (q8 + 1) : r8 * (q8 + 1) + (xcd - r8) * q8) + seqq;
    const int split = wgid / ntile;
    const int tile = wgid % ntile;
    // GROUP_M=4 supertiling (M/256 divisible by 4 for all uses)
    const int grp = tile / (4 * gx), rem = tile % (4 * gx);
    const int m0 = (grp * 4 + (rem & 3)) * 256, n0 = (rem >> 2) * 256;
    const int kb0 = split * Ks;
    const int niter = Ks >> 7;                    // 2 K-tiles per iteration (Ks % 128 == 0)

    // staging source pointers (pre-swizzled), advance by kt*64 elements
    const bf16* aS[2][2]; const bf16* bS[2][2];   // [half][c]
    int sOff[2];
#pragma unroll
    for (int c = 0; c < 2; ++c) {
        const int s = (c * 512 + t512) * 16;            // linear byte slot
        const int pp = s ^ (((s >> 7) & 7) << 4);       // nominal position (involution)
        const int row = pp >> 7, colE = (pp & 127) >> 1;
        sOff[c] = s;
#pragma unroll
        for (int hs = 0; hs < 2; ++hs) {
            aS[hs][c] = A + (size_t)(m0 + hs * 128 + row) * K + kb0 + colE;
            const int rg = n0 + hs * 128 + row;
            if (EP == 4) {
                const int g = rg >> 4;
                const bf16* src = (g & 1) ? Bt2 : Bt;
                const int j = ((g >> 1) << 4) + (rg & 15);
                bS[hs][c] = src + (size_t)j * K + kb0 + colE;
            } else {
                bS[hs][c] = Bt + (size_t)rg * K + kb0 + colE;
            }
        }
    }
    auto stA = [&](int buf, int kt, int hs) {      // one A half-tile: 2 gl16/thread
        char* base = smem + (buf * 2 + hs) * 16384;
        gl16(aS[hs][0] + (kt << 6), base + sOff[0]);
        gl16(aS[hs][1] + (kt << 6), base + sOff[1]);
    };
    auto stB = [&](int buf, int kt, int hs) {      // one B half-tile
        char* base = smem + 65536 + (buf * 2 + hs) * 16384;
        gl16(bS[hs][0] + (kt << 6), base + sOff[0]);
        gl16(bS[hs][1] + (kt << 6), base + sOff[1]);
    };

    // per-wave LDS read bases (loop-invariant)
    const char* A0m = smem + (0 * 2 + wm) * 16384;
    const char* A1m = smem + (1 * 2 + wm) * 16384;
    const char* B0m = smem + 65536 + (0 * 2 + (wn >> 1)) * 16384;
    const char* B1m = smem + 65536 + (1 * 2 + (wn >> 1)) * 16384;

    f32x4 acc[8][4] = {};
    bf16x8 bfr[4][2];
    bf16x8 x0, x1, x2, x3;

#define SBAR __builtin_amdgcn_s_barrier()
#define LGKM0 do { asm volatile("s_waitcnt lgkmcnt(0)" ::: "memory"); \
                   __builtin_amdgcn_sched_barrier(0); } while (0)
#define LGKM8 do { asm volatile("s_waitcnt lgkmcnt(8)" ::: "memory"); \
                   __builtin_amdgcn_sched_barrier(0); } while (0)
#define WVM(n) do { asm volatile("s_waitcnt vmcnt(" #n ")" ::: "memory"); \
                    __builtin_amdgcn_sched_barrier(0); } while (0)
#define LDA4(base, mf0) do { \
    x0 = *(const bf16x8*)((base) + (((mf0) * 16 + lr) * 128) + ((lg * 16) ^ swz)); \
    x1 = *(const bf16x8*)((base) + (((mf0) * 16 + lr) * 128) + ((64 + lg * 16) ^ swz)); \
    x2 = *(const bf16x8*)((base) + ((((mf0) + 1) * 16 + lr) * 128) + ((lg * 16) ^ swz)); \
    x3 = *(const bf16x8*)((base) + ((((mf0) + 1) * 16 + lr) * 128) + ((64 + lg * 16) ^ swz)); \
    } while (0)
#define LDB8(base) do { \
    _Pragma("unroll") \
    for (int nf = 0; nf < 4; ++nf) { \
        bfr[nf][0] = *(const bf16x8*)((base) + ((bofs + nf * 16 + lr) * 128) + ((lg * 16) ^ swz)); \
        bfr[nf][1] = *(const bf16x8*)((base) + ((bofs + nf * 16 + lr) * 128) + ((64 + lg * 16) ^ swz)); \
    } } while (0)
#define MFMA_PH(mf0) do { \
    __builtin_amdgcn_s_setprio(1); \
    _Pragma("unroll") \
    for (int nf = 0; nf < 4; ++nf) { \
        acc[(mf0)][nf]     = MFMA16(x0, bfr[nf][0], acc[(mf0)][nf]); \
        acc[(mf0)][nf]     = MFMA16(x1, bfr[nf][1], acc[(mf0)][nf]); \
        acc[(mf0) + 1][nf] = MFMA16(x2, bfr[nf][0], acc[(mf0) + 1][nf]); \
        acc[(mf0) + 1][nf] = MFMA16(x3, bfr[nf][1], acc[(mf0) + 1][nf]); \
    } \
    __builtin_amdgcn_s_setprio(0); } while (0)

    // prologue: tile0 B+A (8 gl16), tile1 B (4 gl16); tile1 A staged in iter0 ph1/ph2
    stB(0, 0, 0); stB(0, 0, 1); stA(0, 0, 0); stA(0, 0, 1);
    stB(1, 1, 0); stB(1, 1, 1);
    WVM(4);                 // tile0's 8 landed; tile1-B still in flight
    SBAR;                   // publish

    for (int t = 0; t < niter; ++t) {
        const bool pf = (t + 1 < niter);
        const int k1 = 2 * t + 1, k2 = 2 * t + 2, k3 = 2 * t + 3;

        // ---- ph1: K-tile 2t quadrant 0 (+ stage A of buf1) ----
        LDB8(B0m);
        LDA4(A0m, 0);
        stA(1, k1, 0);
        LGKM8;
        SBAR; LGKM0; MFMA_PH(0); SBAR;
        // ---- ph2 ----
        LDA4(A0m, 2);
        stA(1, k1, 1);
        SBAR; LGKM0; MFMA_PH(2); SBAR;
        // ---- ph3 ----
        LDA4(A0m, 4);
        if (pf) stB(0, k2, 0);
        SBAR; LGKM0; MFMA_PH(4); SBAR;
        // ---- ph4: wait covers {prev B1 halves, this A1 halves} for ph5-8 ----
        if (pf) { WVM(2); } else { WVM(0); }
        LDA4(A0m, 6);
        if (pf) stB(0, k2, 1);
        SBAR; LGKM0; MFMA_PH(6); SBAR;
        // ---- ph5: K-tile 2t+1 quadrant 0 (+ stage A of buf0) ----
        LDB8(B1m);
        LDA4(A1m, 0);
        if (pf) stA(0, k2, 0);
        LGKM8;
        SBAR; LGKM0; MFMA_PH(0); SBAR;
        // ---- ph6 ----
        LDA4(A1m, 2);
        if (pf) stA(0, k2, 1);
        SBAR; LGKM0; MFMA_PH(2); SBAR;
        // ---- ph7 ----
        LDA4(A1m, 4);
        if (pf) stB(1, k3, 0);
        SBAR; LGKM0; MFMA_PH(4); SBAR;
        // ---- ph8: wait covers {this B0',A0'} for next ph1 ----
        if (pf) WVM(2);
        LDA4(A1m, 6);
        if (pf) stB(1, k3, 1);
        SBAR; LGKM0; MFMA_PH(6); SBAR;
    }
#undef SBAR
#undef LGKM0
#undef LGKM8
#undef WVM
#undef LDA4
#undef LDB8
#undef MFMA_PH

    // ---- epilogue ----
    if (EP == 4) {
        // pairs (nf, nf+1) = (w1, w3) products of the same HID column, same lane
        const int jb = (n0 >> 1) + wn * 32;
        const int NH = N >> 1;                  // = HID
#pragma unroll
        for (int mf = 0; mf < 8; ++mf)
#pragma unroll
            for (int pp = 0; pp < 4; pp += 2) {
                const int row = m0 + wm * 128 + mf * 16 + lg * 4;
                const int j = jb + (pp >> 1) * 16 + lr;
#pragma unroll
                for (int r = 0; r < 4; ++r) {
                    const float a = acc[mf][pp][r];
                    const float b = acc[mf][pp + 1][r];
                    const float s = a / (1.0f + __expf(-a));
                    Cb[(size_t)(row + r) * NH + j] = __float2bfloat16(s * b);
                }
            }
    } else {
        float* pf_base = Pf + (size_t)split * M * N;
#pragma unroll
        for (int mf = 0; mf < 8; ++mf)
#pragma unroll
            for (int nf = 0; nf < 4; ++nf) {
                const int row = m0 + wm * 128 + mf * 16 + lg * 4;
                const int col = n0 + wn * 64 + nf * 16 + lr;
#pragma unroll
                for (int r = 0; r < 4; ++r) {
                    const size_t idx = (size_t)(row + r) * N + col;
                    const float v = acc[mf][nf][r];
                    if (EP == 0) Cb[idx] = __float2bfloat16(v);
                    else         pf_base[idx] = v;
                }
            }
    }
}

// ---------------- causal flash attention: paired q-tiles, 8 waves, shared KV ----------------
// Block = (pair bx, head): waves 0-3 -> q-tile bx (light), waves 4-7 -> q-tile 31-bx (heavy).
// Each SIMD gets 1 light + 1 heavy wave => constant 33 tile-computes/SIMD (perfect balance).
// K double-buffered (prefetch survives raw s_barrier via counted vmcnt); V single-buffered
// (staged at iter top, landed by mid-iter vmcnt wait). KV staged ONCE per pair.
__global__ __launch_bounds__(512) void attn_fwd_k(
    const bf16* __restrict__ qkv, const bf16* __restrict__ vT, bf16* __restrict__ ctx)
{
    const int tid = threadIdx.x;
    const int w8 = tid >> 6, lane = tid & 63;
    const int lr = lane & 15, lg = lane >> 4;
    const int w = w8 & 3, tsel = w8 >> 2;
    const int h = blockIdx.y;
    const int bx = blockIdx.x;                    // 0..15
    const int qidx = tsel ? (31 - bx) : bx;
    const int q0b = qidx * 64;
    const int myNt = qidx + 1;                    // tiles this wave-group computes
    const int nt = 32 - bx;                       // loop bound (heavy group's need)

    __shared__ __align__(16) unsigned short Kt[2][64 * 128];   // 32KB
    __shared__ __align__(16) unsigned short Vt[128 * 64];      // 16KB
    __shared__ __align__(16) unsigned short Pp[8][16 * 64];    // 16KB

    const char* kbase = (const char*)(qkv + DIM + h * HEAD_DIM);
    const char* vbase = (const char*)(vT + (size_t)h * HEAD_DIM * SEQ);

    const int krow_c = tid >> 4;                  // 0..31
    const int kcolB  = (tid & 15) * 16;
    const int vrow_c = tid >> 3;                  // 0..63
    const int vcolB  = (tid & 7) * 16;

    auto stageK = [&](int buf, int kb) {          // 2 gl16/thread
#pragma unroll
        for (int c = 0; c < 2; ++c) {
            const int r = c * 32 + krow_c;
            gl16(kbase + (size_t)(kb + r) * (SQKV * 2) + (kcolB ^ ((r & 7) << 4)),
                 &Kt[buf][c * 4096 + tid * 8]);
        }
    };
    auto stageV = [&](int kb) {                   // 2 gl16/thread
#pragma unroll
        for (int c = 0; c < 2; ++c) {
            const int r = c * 64 + vrow_c;
            gl16(vbase + (size_t)r * (SEQ * 2) + kb * 2 + (vcolB ^ ((r & 7) << 4)),
                 &Vt[c * 4096 + tid * 8]);
        }
    };

    bf16x8 qf[4];
    const bf16* qrow = qkv + (size_t)(q0b + w * 16 + lr) * SQKV + h * HEAD_DIM;
#pragma unroll
    for (int dt = 0; dt < 4; ++dt)
        qf[dt] = *(const bf16x8*)(qrow + dt * 32 + lg * 8);

    f32x4 o[8] = {};
    float m[4], l[4];
#pragma unroll
    for (int j = 0; j < 4; ++j) { m[j] = -3e38f; l[j] = 0.0f; }
    const float scale = 0.08838834764831845f;

    stageK(0, 0);
    asm volatile("s_waitcnt vmcnt(0)" ::: "memory");
    __builtin_amdgcn_sched_barrier(0);
    __builtin_amdgcn_s_barrier();

    int cur = 0;
    for (int t = 0; t < nt; ++t) {
        const int kb = t * 64;
        const bool pf = (t + 1 < nt);
        stageV(kb);                               // V(t): needed mid-iter
        if (pf) stageK(cur ^ 1, kb + 64);         // K(t+1): needed next iter
        const bool act = (t < myNt);

        if (act) {
            f32x4 s[4] = {};
            __builtin_amdgcn_s_setprio(1);
#pragma unroll
            for (int ss = 0; ss < 4; ++ss) {
                const int r = ss * 16 + lr;
                const int sw = (r & 7) << 3;
#pragma unroll
                for (int dt = 0; dt < 4; ++dt) {
                    bf16x8 kf = *(const bf16x8*)&Kt[cur][r * 128 + ((dt * 32 + lg * 8) ^ sw)];
                    s[ss] = MFMA16(qf[dt], kf, s[ss]);
                }
            }
            __builtin_amdgcn_s_setprio(0);

            float al[4];
#pragma unroll
            for (int j = 0; j < 4; ++j) {
                const int qi = q0b + w * 16 + lg * 4 + j;
                const int prow = lg * 4 + j;
                const int psw = (prow & 7) << 3;
                float a[4];
#pragma unroll
                for (int ss = 0; ss < 4; ++ss)
                    a[ss] = s[ss][j] * scale + ((kb + ss * 16 + lr) > qi ? -1e9f : 0.0f);
                float mx = fmaxf(fmaxf(a[0], a[1]), fmaxf(a[2], a[3]));
                mx = fmaxf(mx, __shfl_xor(mx, 1));
                mx = fmaxf(mx, __shfl_xor(mx, 2));
                mx = fmaxf(mx, __shfl_xor(mx, 4));
                mx = fmaxf(mx, __shfl_xor(mx, 8));
                const float mn = fmaxf(m[j], mx);
                const float asc = __expf(m[j] - mn);
                float e0 = __expf(a[0] - mn), e1 = __expf(a[1] - mn);
                float e2 = __expf(a[2] - mn), e3 = __expf(a[3] - mn);
                float rs = (e0 + e1) + (e2 + e3);
                rs += __shfl_xor(rs, 1); rs += __shfl_xor(rs, 2);
                rs += __shfl_xor(rs, 4); rs += __shfl_xor(rs, 8);
                l[j] = l[j] * asc + rs;
                m[j] = mn;
                al[j] = asc;
                Pp[w8][prow * 64 + ((lr)      ^ psw)] = f2bu(e0);
                Pp[w8][prow * 64 + ((16 + lr) ^ psw)] = f2bu(e1);
                Pp[w8][prow * 64 + ((32 + lr) ^ psw)] = f2bu(e2);
                Pp[w8][prow * 64 + ((48 + lr) ^ psw)] = f2bu(e3);
            }
#pragma unroll
            for (int d2 = 0; d2 < 8; ++d2)
#pragma unroll
                for (int j = 0; j < 4; ++j) o[d2][j] *= al[j];
        }

        // V(t) landed (leave K(t+1)'s 2 loads in flight), publish block-wide
        if (pf) { asm volatile("s_waitcnt vmcnt(2)" ::: "memory"); }
        else    { asm volatile("s_waitcnt vmcnt(0)" ::: "memory"); }
        __builtin_amdgcn_sched_barrier(0);
        __builtin_amdgcn_s_barrier();

        if (act) {
            asm volatile("s_waitcnt lgkmcnt(0)" ::: "memory");
            __builtin_amdgcn_sched_barrier(0);
            const int asw = (lr & 7) << 3;
            bf16x8 pa0 = *(const bf16x8*)&Pp[w8][lr * 64 + ((lg * 8)      ^ asw)];
            bf16x8 pa1 = *(const bf16x8*)&Pp[w8][lr * 64 + ((32 + lg * 8) ^ asw)];

            __builtin_amdgcn_s_setprio(1);
#pragma unroll
            for (int d2 = 0; d2 < 8; ++d2) {
                const int rv = d2 * 16 + lr;
                const int vsw = (rv & 7) << 3;
                bf16x8 vf0 = *(const bf16x8*)&Vt[rv * 64 + ((lg * 8)      ^ vsw)];
                bf16x8 vf1 = *(const bf16x8*)&Vt[rv * 64 + ((32 + lg * 8) ^ vsw)];
                o[d2] = MFMA16(pa0, vf0, o[d2]);
                o[d2] = MFMA16(pa1, vf1, o[d2]);
            }
            __builtin_amdgcn_s_setprio(0);
        }

        __builtin_amdgcn_s_barrier();   // all Vt/Kt[cur] reads in regs before overwrite
        cur ^= 1;
    }

#pragma unroll
    for (int j = 0; j < 4; ++j) {
        const float inv = 1.0f / l[j];
        bf16* dst = ctx + (size_t)(q0b + w * 16 + lg * 4 + j) * DIM + h * HEAD_DIM + lr;
#pragma unroll
        for (int d2 = 0; d2 < 8; ++d2)
            dst[d2 * 16] = __float2bfloat16(o[d2][j] * inv);
    }
}

// ---------------- host ----------------
extern "C" void kernel_launch(void* const* d_in, const int* in_sizes, int n_in,
                              void* d_out, int out_size, void* d_ws, size_t ws_size,
                              hipStream_t stream)
{
    const float* x   = (const float*)d_in[0];
    const float* fc  = (const float*)d_in[1];
    const float* fs  = (const float*)d_in[2];
    // d_in[3] = mask (unused; causal computed analytically)
    const float* wq  = (const float*)d_in[4];
    const float* wk  = (const float*)d_in[5];
    const float* wv  = (const float*)d_in[6];
    const float* wo  = (const float*)d_in[7];
    const float* w1  = (const float*)d_in[8];
    const float* w2  = (const float*)d_in[9];
    const float* w3  = (const float*)d_in[10];
    const float* anw = (const float*)d_in[11];
    const float* fnw = (const float*)d_in[12];
    float* out = (float*)d_out;

    char* p = (char*)d_ws;
    auto alloc = [&](size_t n) { char* r = p; p += (n + 255) & ~(size_t)255; return r; };
    bf16* wT  = (bf16*)alloc((size_t)HID * DIM * 2);     // reused per weight group
    bf16* hn  = (bf16*)alloc((size_t)SEQ * DIM * 2);     // dead after QKV GEMM
    bf16* qkv = (bf16*)alloc((size_t)SEQ * SQKV * 2);    // dead after attn
    bf16* vt  = (bf16*)alloc((size_t)SEQ * DIM * 2);
    bf16* ctx = (bf16*)alloc((size_t)SEQ * DIM * 2);
    bf16* fn  = (bf16*)alloc((size_t)SEQ * DIM * 2);
    float* h  = (float*)alloc((size_t)SEQ * DIM * 4);
    bf16* g   = (bf16*)alloc((size_t)SEQ * HID * 2);
    float* sk = (float*)alloc((size_t)4 * SEQ * DIM * 4);  // split-K partials (64MB)
    // w3^T aliases hn+qkv (both dead by the time it's written)
    bf16* w3T = hn;

    const dim3 tb32(32, 8);
    const int LDS256 = 131072;
    (void)hipFuncSetAttribute((const void*)gemm256_k<0>,
        hipFuncAttributeMaxDynamicSharedMemorySize, LDS256);
    (void)hipFuncSetAttribute((const void*)gemm256_k<3>,
        hipFuncAttributeMaxDynamicSharedMemorySize, LDS256);
    (void)hipFuncSetAttribute((const void*)gemm256_k<4>,
        hipFuncAttributeMaxDynamicSharedMemorySize, LDS256);

    rmsnorm_bf16_k<<<SEQ, 256, 0, stream>>>(x, anw, hn);

    // fused QKV: wT = [wq^T; wk^T; wv^T] (6144x2048) -> qkv[2048][6144]
    convT3_f32_bf16_k<<<dim3(DIM / 32, DIM / 32, 3), tb32, 0, stream>>>(wq, wk, wv, wT);
    gemm256_k<0><<<(SEQ / 256) * (SQKV / 256), 512, LDS256, stream>>>(
        hn, wT, nullptr, qkv, nullptr, SEQ, SQKV, DIM, SQKV / 256, (SEQ / 256) * (SQKV / 256), DIM);

    rope_qk_k<<<(SEQ * 1024) / 256, 256, 0, stream>>>(qkv, qkv + DIM, fc, fs);
    transpose_bf16_k<<<dim3(DIM / 32, SEQ / 32), tb32, 0, stream>>>(qkv + 2 * DIM, SQKV, vt);

    attn_fwd_k<<<dim3(16, N_HEADS), 512, 0, stream>>>(qkv, vt, ctx);

    // h = x + ctx @ wo : split-K=4 (Ks=512) -> partials, fused reduce+residual+rmsnorm
    convT_f32_bf16_k<<<dim3(DIM / 32, DIM / 32), tb32, 0, stream>>>(wo, wT, DIM, DIM);
    gemm256_k<3><<<(SEQ / 256) * (DIM / 256) * 4, 512, LDS256, stream>>>(
        ctx, wT, nullptr, nullptr, sk, SEQ, DIM, DIM, DIM / 256, (SEQ / 256) * (DIM / 256), 512);
    rmsnorm4_k<<<SEQ, 256, 0, stream>>>(sk, x, fnw, h, fn);

    // fused FFN-up: g = silu(fn@w1) * (fn@w3), single GEMM over N'=16384
    convT_f32_bf16_k<<<dim3(HID / 32, DIM / 32), tb32, 0, stream>>>(w1, wT, DIM, HID);
    convT_f32_bf16_k<<<dim3(HID / 32, DIM / 32), tb32, 0, stream>>>(w3, w3T, DIM, HID);
    gemm256_k<4><<<(SEQ / 256) * ((2 * HID) / 256), 512, LDS256, stream>>>(
        fn, wT, w3T, g, nullptr, SEQ, 2 * HID, DIM, (2 * HID) / 256,
        (SEQ / 256) * ((2 * HID) / 256), DIM);

    // out = h + g @ w2 : split-K=4 (Ks=2048) -> partials, reduce+residual
    convT_f32_bf16_k<<<dim3(DIM / 32, HID / 32), tb32, 0, stream>>>(w2, wT, HID, DIM);
    gemm256_k<3><<<(SEQ / 256) * (DIM / 256) * 4, 512, LDS256, stream>>>(
        g, wT, nullptr, nullptr, sk, SEQ, DIM, HID, DIM / 256, (SEQ / 256) * (DIM / 256), 2048);
    reduce4_k<<<(SEQ * DIM / 4) / 256, 256, 0, stream>>>(sk, h, out);
}

// Round 14
// 448.312 us; speedup vs baseline: 1.1582x; 1.0639x over previous
//
#include <hip/hip_runtime.h>
#include <hip/hip_bf16.h>

#define DIM 2048
#define HEAD_DIM 128
#define N_HEADS 16
#define SEQ 2048
#define HID 8192
#define SQKV 6144   // row stride of fused qkv activation

typedef short bf16x8 __attribute__((ext_vector_type(8)));
typedef float f32x4 __attribute__((ext_vector_type(4)));
using bf16 = __hip_bfloat16;

#define MFMA16(a, b, c) __builtin_amdgcn_mfma_f32_16x16x32_bf16(a, b, c, 0, 0, 0)

__device__ __forceinline__ unsigned short f2bu(float f) {
    union { bf16 b; unsigned short u; } cv;
    cv.b = __float2bfloat16(f);
    return cv.u;
}
__device__ __forceinline__ float bu2f(unsigned short u) {
    union { unsigned short u; bf16 b; } cv;
    cv.u = u;
    return __bfloat162float(cv.b);
}

// async global -> LDS, 16B per lane (dest must be lane-linear per wave)
__device__ __forceinline__ void gl16(const void* g, void* l) {
    __builtin_amdgcn_global_load_lds(
        (const __attribute__((address_space(1))) unsigned int*)g,
        (__attribute__((address_space(3))) unsigned int*)l, 16, 0, 0);
}

// ---------------- rmsnorm (fp32 in -> bf16 out) ----------------
__global__ __launch_bounds__(256) void rmsnorm_bf16_k(
    const float* __restrict__ x, const float* __restrict__ w, bf16* __restrict__ y)
{
    const int row = blockIdx.x;
    const int tid = threadIdx.x;
    const float* xr = x + (size_t)row * DIM;
    float4 v0 = ((const float4*)xr)[tid];
    float4 v1 = ((const float4*)xr)[tid + 256];
    float ss = v0.x*v0.x + v0.y*v0.y + v0.z*v0.z + v0.w*v0.w
             + v1.x*v1.x + v1.y*v1.y + v1.z*v1.z + v1.w*v1.w;
    for (int o = 32; o > 0; o >>= 1) ss += __shfl_down(ss, o);
    __shared__ float red[4];
    if ((tid & 63) == 0) red[tid >> 6] = ss;
    __syncthreads();
    float tot = red[0] + red[1] + red[2] + red[3];
    float r = rsqrtf(tot * (1.0f / DIM) + 1e-6f);
    float4 w0 = ((const float4*)w)[tid];
    float4 w1 = ((const float4*)w)[tid + 256];
    ushort4 o0, o1;
    o0.x = f2bu(v0.x * r * w0.x); o0.y = f2bu(v0.y * r * w0.y);
    o0.z = f2bu(v0.z * r * w0.z); o0.w = f2bu(v0.w * r * w0.w);
    o1.x = f2bu(v1.x * r * w1.x); o1.y = f2bu(v1.y * r * w1.y);
    o1.z = f2bu(v1.z * r * w1.z); o1.w = f2bu(v1.w * r * w1.w);
    ushort4* yr = (ushort4*)(y + (size_t)row * DIM);
    yr[tid] = o0;
    yr[tid + 256] = o1;
}

// ---------------- split-K(bf16) reduce + residual + rmsnorm (fp32 h out, bf16 fn out) ----------------
// thread handles 8 contiguous elems at tid*8
__global__ __launch_bounds__(256) void rmsnorm4_k(
    const bf16* __restrict__ part, const float* __restrict__ x,
    const float* __restrict__ w, float* __restrict__ hout, bf16* __restrict__ y)
{
    const int row = blockIdx.x;
    const int tid = threadIdx.x;
    const size_t base = (size_t)row * DIM + tid * 8;
    const size_t SP = (size_t)SEQ * DIM;
    float4 a0 = *(const float4*)(x + base);
    float4 a1 = *(const float4*)(x + base + 4);
    bf16x8 p0 = *(const bf16x8*)(part + base);
    bf16x8 p1 = *(const bf16x8*)(part + SP + base);
    bf16x8 p2 = *(const bf16x8*)(part + 2 * SP + base);
    bf16x8 p3 = *(const bf16x8*)(part + 3 * SP + base);
    float r8[8];
    float ss = 0.0f;
#pragma unroll
    for (int e = 0; e < 8; ++e) {
        const float xa = e < 4 ? (&a0.x)[e] : (&a1.x)[e - 4];
        const float v = xa + ((bu2f((unsigned short)p0[e]) + bu2f((unsigned short)p1[e]))
                            + (bu2f((unsigned short)p2[e]) + bu2f((unsigned short)p3[e])));
        r8[e] = v;
        ss += v * v;
    }
    *(float4*)(hout + base)     = make_float4(r8[0], r8[1], r8[2], r8[3]);
    *(float4*)(hout + base + 4) = make_float4(r8[4], r8[5], r8[6], r8[7]);
    for (int o = 32; o > 0; o >>= 1) ss += __shfl_down(ss, o);
    __shared__ float red[4];
    if ((tid & 63) == 0) red[tid >> 6] = ss;
    __syncthreads();
    float tot = red[0] + red[1] + red[2] + red[3];
    float r = rsqrtf(tot * (1.0f / DIM) + 1e-6f);
    float4 w0 = *(const float4*)(w + tid * 8);
    float4 w1 = *(const float4*)(w + tid * 8 + 4);
    bf16x8 o8;
#pragma unroll
    for (int e = 0; e < 8; ++e) {
        const float ww = e < 4 ? (&w0.x)[e] : (&w1.x)[e - 4];
        o8[e] = (short)f2bu(r8[e] * r * ww);
    }
    *(bf16x8*)((unsigned short*)y + base) = o8;
}

// ---------------- split-K(bf16) reduce + residual (fp32 out) ----------------
__global__ __launch_bounds__(256) void reduce4_k(
    const bf16* __restrict__ part, const float* __restrict__ h, float* __restrict__ out)
{
    const size_t i = ((size_t)blockIdx.x * 256 + threadIdx.x) * 8;
    const size_t SP = (size_t)SEQ * DIM;
    float4 a0 = *(const float4*)(h + i);
    float4 a1 = *(const float4*)(h + i + 4);
    bf16x8 p0 = *(const bf16x8*)(part + i);
    bf16x8 p1 = *(const bf16x8*)(part + SP + i);
    bf16x8 p2 = *(const bf16x8*)(part + 2 * SP + i);
    bf16x8 p3 = *(const bf16x8*)(part + 3 * SP + i);
    float r8[8];
#pragma unroll
    for (int e = 0; e < 8; ++e) {
        const float xa = e < 4 ? (&a0.x)[e] : (&a1.x)[e - 4];
        r8[e] = xa + ((bu2f((unsigned short)p0[e]) + bu2f((unsigned short)p1[e]))
                    + (bu2f((unsigned short)p2[e]) + bu2f((unsigned short)p3[e])));
    }
    *(float4*)(out + i)     = make_float4(r8[0], r8[1], r8[2], r8[3]);
    *(float4*)(out + i + 4) = make_float4(r8[4], r8[5], r8[6], r8[7]);
}

// ---------------- fp32 [R][C] -> bf16 [C][R], 64x64 tile, vectorized (G13) ----------------
// load float4/lane, transpose via bf16 LDS, store bf16x8 (16B)/lane
__device__ __forceinline__ void convT64_body(
    const float* __restrict__ in, bf16* __restrict__ out, int R, int C,
    int bx, int by)
{
    __shared__ unsigned short t[64][72];      // row stride 144B (16B-aligned)
    const int tid = threadIdx.x;
    const int x0 = bx * 64;                   // c
    const int y0 = by * 64;                   // r
    const int tx = tid & 15, ty = tid >> 4;
#pragma unroll
    for (int i = 0; i < 4; ++i) {
        const int row = ty + i * 16;
        float4 v = *(const float4*)(in + (size_t)(y0 + row) * C + x0 + tx * 4);
        t[tx * 4 + 0][row] = f2bu(v.x);
        t[tx * 4 + 1][row] = f2bu(v.y);
        t[tx * 4 + 2][row] = f2bu(v.z);
        t[tx * 4 + 3][row] = f2bu(v.w);
    }
    __syncthreads();
    const int rx = tid & 7, cy = tid >> 3;
#pragma unroll
    for (int i = 0; i < 2; ++i) {
        const int c = cy + i * 32;
        bf16x8 v = *(const bf16x8*)&t[c][rx * 8];
        *(bf16x8*)(out + (size_t)(x0 + c) * R + y0 + rx * 8) = v;
    }
}

__global__ __launch_bounds__(256) void convT64_k(
    const float* __restrict__ in, bf16* __restrict__ out, int R, int C)
{
    convT64_body(in, out, R, C, blockIdx.x, blockIdx.y);
}

// z selects wq/wk/wv -> one [3*DIM][DIM] B^T buffer
__global__ __launch_bounds__(256) void convT64q_k(
    const float* __restrict__ wq, const float* __restrict__ wk,
    const float* __restrict__ wv, bf16* __restrict__ out)
{
    const int z = blockIdx.z;
    const float* in = z == 0 ? wq : (z == 1 ? wk : wv);
    convT64_body(in, out + (size_t)z * DIM * DIM, DIM, DIM, blockIdx.x, blockIdx.y);
}

// z selects w1/w3 (both [DIM][HID] -> [HID][DIM])
__global__ __launch_bounds__(256) void convT64f_k(
    const float* __restrict__ w1, const float* __restrict__ w3,
    bf16* __restrict__ o1, bf16* __restrict__ o3)
{
    const int z = blockIdx.z;
    convT64_body(z ? w3 : w1, z ? o3 : o1, DIM, HID, blockIdx.x, blockIdx.y);
}

// ---------------- bf16 transpose with src stride (vt[d][s] = in[s][d]) ----------------
__global__ __launch_bounds__(256) void transpose_bf16_k(
    const bf16* __restrict__ in, int istride, bf16* __restrict__ out)
{
    __shared__ unsigned short t[32][33];
    const int tx = threadIdx.x & 31, ty = threadIdx.x >> 5;
    const int x = blockIdx.x * 32 + tx;       // d
    const int y0 = blockIdx.y * 32;           // s
    const unsigned short* inu = (const unsigned short*)in;
    unsigned short* outu = (unsigned short*)out;
#pragma unroll
    for (int i = 0; i < 4; ++i)
        t[ty + i * 8][tx] = inu[(size_t)(y0 + ty + i * 8) * istride + x];
    __syncthreads();
    const int x2 = blockIdx.y * 32 + tx;
    const int y2 = blockIdx.x * 32;
#pragma unroll
    for (int i = 0; i < 4; ++i)
        outu[(size_t)(y2 + ty + i * 8) * SEQ + x2] = t[tx][ty + i * 8];
}

// ---------------- RoPE in-place on strided bf16 q,k ----------------
__global__ __launch_bounds__(256) void rope_qk_k(
    bf16* __restrict__ q, bf16* __restrict__ k,
    const float* __restrict__ cosb, const float* __restrict__ sinb)
{
    const int gid = blockIdx.x * 256 + threadIdx.x;   // < SEQ * 1024
    const int s = gid >> 10;
    const int p = gid & 1023;
    const int h = p >> 6, j = p & 63;
    const size_t off = (size_t)s * SQKV + h * HEAD_DIM + 2 * j;
    const float c = cosb[s * 64 + j], sn = sinb[s * 64 + j];
    float xr = __bfloat162float(q[off]), xi = __bfloat162float(q[off + 1]);
    q[off]     = __float2bfloat16(xr * c - xi * sn);
    q[off + 1] = __float2bfloat16(xr * sn + xi * c);
    xr = __bfloat162float(k[off]); xi = __bfloat162float(k[off + 1]);
    k[off]     = __float2bfloat16(xr * c - xi * sn);
    k[off + 1] = __float2bfloat16(xr * sn + xi * c);
}

// ---------------- 256x256 GEMM, m201 8-phase skeleton, BK=64 x2/iter, split-K ----------------
// EP 0: store bf16    EP 3: bf16 partial store (to Cb + split*M*N)
// EP 4: fused w1|w3 -> silu(w1part)*w3part (B rows interleaved per-16 from Bt/Bt2)
template <int EP>
__global__ __launch_bounds__(512, 1) void gemm256_k(
    const bf16* __restrict__ A, const bf16* __restrict__ Bt, const bf16* __restrict__ Bt2,
    bf16* __restrict__ Cb,
    int M, int N, int K, int gx, int ntile, int Ks)
{
    extern __shared__ char smem[];
    const int t512 = threadIdx.x;
    const int w = t512 >> 6, lane = t512 & 63;
    const int lr = lane & 15, lg = lane >> 4;
    const int wm = w >> 2, wn = w & 3;           // 2 x 4 wave grid
    const int bofs = (wn & 1) * 64;              // B row offset inside its half
    const int swz = (lr & 7) << 4;               // ds_read swizzle

    // XCD-bijective block swizzle (m204)
    const int nwg = gridDim.x;                    // = ntile * splitk
    const int q8 = nwg >> 3, r8 = nwg & 7;
    const int xcd = blockIdx.x & 7, seqq = blockIdx.x >> 3;
    const int wgid = (xcd < r8 ? xcd * (q8 + 1) : r8 * (q8 + 1) + (xcd - r8) * q8) + seqq;
    const int split = wgid / ntile;
    const int tile = wgid % ntile;
    // GROUP_M=4 supertiling (M/256 divisible by 4 for all uses)
    const int grp = tile / (4 * gx), rem = tile % (4 * gx);
    const int m0 = (grp * 4 + (rem & 3)) * 256, n0 = (rem >> 2) * 256;
    const int kb0 = split * Ks;
    const int niter = Ks >> 7;                    // 2 K-tiles per iteration (Ks % 128 == 0)

    // staging source pointers (pre-swizzled), advance by kt*64 elements
    const bf16* aS[2][2]; const bf16* bS[2][2];   // [half][c]
    int sOff[2];
#pragma unroll
    for (int c = 0; c < 2; ++c) {
        const int s = (c * 512 + t512) * 16;            // linear byte slot
        const int pp = s ^ (((s >> 7) & 7) << 4);       // nominal position (involution)
        const int row = pp >> 7, colE = (pp & 127) >> 1;
        sOff[c] = s;
#pragma unroll
        for (int hs = 0; hs < 2; ++hs) {
            aS[hs][c] = A + (size_t)(m0 + hs * 128 + row) * K + kb0 + colE;
            const int rg = n0 + hs * 128 + row;
            if (EP == 4) {
                const int g = rg >> 4;
                const bf16* src = (g & 1) ? Bt2 : Bt;
                const int j = ((g >> 1) << 4) + (rg & 15);
                bS[hs][c] = src + (size_t)j * K + kb0 + colE;
            } else {
                bS[hs][c] = Bt + (size_t)rg * K + kb0 + colE;
            }
        }
    }
    auto stA = [&](int buf, int kt, int hs) {      // one A half-tile: 2 gl16/thread
        char* base = smem + (buf * 2 + hs) * 16384;
        gl16(aS[hs][0] + (kt << 6), base + sOff[0]);
        gl16(aS[hs][1] + (kt << 6), base + sOff[1]);
    };
    auto stB = [&](int buf, int kt, int hs) {      // one B half-tile
        char* base = smem + 65536 + (buf * 2 + hs) * 16384;
        gl16(bS[hs][0] + (kt << 6), base + sOff[0]);
        gl16(bS[hs][1] + (kt << 6), base + sOff[1]);
    };

    // per-wave LDS read bases (loop-invariant)
    const char* A0m = smem + (0 * 2 + wm) * 16384;
    const char* A1m = smem + (1 * 2 + wm) * 16384;
    const char* B0m = smem + 65536 + (0 * 2 + (wn >> 1)) * 16384;
    const char* B1m = smem + 65536 + (1 * 2 + (wn >> 1)) * 16384;

    f32x4 acc[8][4] = {};
    bf16x8 bfr[4][2];
    bf16x8 x0, x1, x2, x3;

#define SBAR __builtin_amdgcn_s_barrier()
#define LGKM0 do { asm volatile("s_waitcnt lgkmcnt(0)" ::: "memory"); \
                   __builtin_amdgcn_sched_barrier(0); } while (0)
#define LGKM8 do { asm volatile("s_waitcnt lgkmcnt(8)" ::: "memory"); \
                   __builtin_amdgcn_sched_barrier(0); } while (0)
#define WVM(n) do { asm volatile("s_waitcnt vmcnt(" #n ")" ::: "memory"); \
                    __builtin_amdgcn_sched_barrier(0); } while (0)
#define LDA4(base, mf0) do { \
    x0 = *(const bf16x8*)((base) + (((mf0) * 16 + lr) * 128) + ((lg * 16) ^ swz)); \
    x1 = *(const bf16x8*)((base) + (((mf0) * 16 + lr) * 128) + ((64 + lg * 16) ^ swz)); \
    x2 = *(const bf16x8*)((base) + ((((mf0) + 1) * 16 + lr) * 128) + ((lg * 16) ^ swz)); \
    x3 = *(const bf16x8*)((base) + ((((mf0) + 1) * 16 + lr) * 128) + ((64 + lg * 16) ^ swz)); \
    } while (0)
#define LDB8(base) do { \
    _Pragma("unroll") \
    for (int nf = 0; nf < 4; ++nf) { \
        bfr[nf][0] = *(const bf16x8*)((base) + ((bofs + nf * 16 + lr) * 128) + ((lg * 16) ^ swz)); \
        bfr[nf][1] = *(const bf16x8*)((base) + ((bofs + nf * 16 + lr) * 128) + ((64 + lg * 16) ^ swz)); \
    } } while (0)
#define MFMA_PH(mf0) do { \
    __builtin_amdgcn_s_setprio(1); \
    _Pragma("unroll") \
    for (int nf = 0; nf < 4; ++nf) { \
        acc[(mf0)][nf]     = MFMA16(x0, bfr[nf][0], acc[(mf0)][nf]); \
        acc[(mf0)][nf]     = MFMA16(x1, bfr[nf][1], acc[(mf0)][nf]); \
        acc[(mf0) + 1][nf] = MFMA16(x2, bfr[nf][0], acc[(mf0) + 1][nf]); \
        acc[(mf0) + 1][nf] = MFMA16(x3, bfr[nf][1], acc[(mf0) + 1][nf]); \
    } \
    __builtin_amdgcn_s_setprio(0); } while (0)

    // prologue: tile0 B+A (8 gl16), tile1 B (4 gl16); tile1 A staged in iter0 ph1/ph2
    stB(0, 0, 0); stB(0, 0, 1); stA(0, 0, 0); stA(0, 0, 1);
    stB(1, 1, 0); stB(1, 1, 1);
    WVM(4);                 // tile0's 8 landed; tile1-B still in flight
    SBAR;                   // publish

    for (int t = 0; t < niter; ++t) {
        const bool pf = (t + 1 < niter);
        const int k1 = 2 * t + 1, k2 = 2 * t + 2, k3 = 2 * t + 3;

        // ---- ph1 ----
        LDB8(B0m);
        LDA4(A0m, 0);
        stA(1, k1, 0);
        LGKM8;
        SBAR; LGKM0; MFMA_PH(0); SBAR;
        // ---- ph2 ----
        LDA4(A0m, 2);
        stA(1, k1, 1);
        SBAR; LGKM0; MFMA_PH(2); SBAR;
        // ---- ph3 ----
        LDA4(A0m, 4);
        if (pf) stB(0, k2, 0);
        SBAR; LGKM0; MFMA_PH(4); SBAR;
        // ---- ph4 ----
        if (pf) { WVM(2); } else { WVM(0); }
        LDA4(A0m, 6);
        if (pf) stB(0, k2, 1);
        SBAR; LGKM0; MFMA_PH(6); SBAR;
        // ---- ph5 ----
        LDB8(B1m);
        LDA4(A1m, 0);
        if (pf) stA(0, k2, 0);
        LGKM8;
        SBAR; LGKM0; MFMA_PH(0); SBAR;
        // ---- ph6 ----
        LDA4(A1m, 2);
        if (pf) stA(0, k2, 1);
        SBAR; LGKM0; MFMA_PH(2); SBAR;
        // ---- ph7 ----
        LDA4(A1m, 4);
        if (pf) stB(1, k3, 0);
        SBAR; LGKM0; MFMA_PH(4); SBAR;
        // ---- ph8 ----
        if (pf) WVM(2);
        LDA4(A1m, 6);
        if (pf) stB(1, k3, 1);
        SBAR; LGKM0; MFMA_PH(6); SBAR;
    }
#undef SBAR
#undef LGKM0
#undef LGKM8
#undef WVM
#undef LDA4
#undef LDB8
#undef MFMA_PH

    // ---- epilogue ----
    if (EP == 4) {
        // pairs (nf, nf+1) = (w1, w3) products of the same HID column, same lane
        const int jb = (n0 >> 1) + wn * 32;
        const int NH = N >> 1;                  // = HID
#pragma unroll
        for (int mf = 0; mf < 8; ++mf)
#pragma unroll
            for (int pp = 0; pp < 4; pp += 2) {
                const int row = m0 + wm * 128 + mf * 16 + lg * 4;
                const int j = jb + (pp >> 1) * 16 + lr;
#pragma unroll
                for (int r = 0; r < 4; ++r) {
                    const float a = acc[mf][pp][r];
                    const float b = acc[mf][pp + 1][r];
                    const float s = a / (1.0f + __expf(-a));
                    Cb[(size_t)(row + r) * NH + j] = __float2bfloat16(s * b);
                }
            }
    } else {
        bf16* cb = (EP == 3) ? Cb + (size_t)split * M * N : Cb;
#pragma unroll
        for (int mf = 0; mf < 8; ++mf)
#pragma unroll
            for (int nf = 0; nf < 4; ++nf) {
                const int row = m0 + wm * 128 + mf * 16 + lg * 4;
                const int col = n0 + wn * 64 + nf * 16 + lr;
#pragma unroll
                for (int r = 0; r < 4; ++r)
                    cb[(size_t)(row + r) * N + col] = __float2bfloat16(acc[mf][nf][r]);
            }
    }
}

// ---------------- causal flash attention: paired q-tiles, 8 waves, shared KV ----------------
__global__ __launch_bounds__(512) void attn_fwd_k(
    const bf16* __restrict__ qkv, const bf16* __restrict__ vT, bf16* __restrict__ ctx)
{
    const int tid = threadIdx.x;
    const int w8 = tid >> 6, lane = tid & 63;
    const int lr = lane & 15, lg = lane >> 4;
    const int w = w8 & 3, tsel = w8 >> 2;
    const int h = blockIdx.y;
    const int bx = blockIdx.x;                    // 0..15
    const int qidx = tsel ? (31 - bx) : bx;
    const int q0b = qidx * 64;
    const int myNt = qidx + 1;
    const int nt = 32 - bx;

    __shared__ __align__(16) unsigned short Kt[2][64 * 128];
    __shared__ __align__(16) unsigned short Vt[128 * 64];
    __shared__ __align__(16) unsigned short Pp[8][16 * 64];

    const char* kbase = (const char*)(qkv + DIM + h * HEAD_DIM);
    const char* vbase = (const char*)(vT + (size_t)h * HEAD_DIM * SEQ);

    const int krow_c = tid >> 4;
    const int kcolB  = (tid & 15) * 16;
    const int vrow_c = tid >> 3;
    const int vcolB  = (tid & 7) * 16;

    auto stageK = [&](int buf, int kb) {
#pragma unroll
        for (int c = 0; c < 2; ++c) {
            const int r = c * 32 + krow_c;
            gl16(kbase + (size_t)(kb + r) * (SQKV * 2) + (kcolB ^ ((r & 7) << 4)),
                 &Kt[buf][c * 4096 + tid * 8]);
        }
    };
    auto stageV = [&](int kb) {
#pragma unroll
        for (int c = 0; c < 2; ++c) {
            const int r = c * 64 + vrow_c;
            gl16(vbase + (size_t)r * (SEQ * 2) + kb * 2 + (vcolB ^ ((r & 7) << 4)),
                 &Vt[c * 4096 + tid * 8]);
        }
    };

    bf16x8 qf[4];
    const bf16* qrow = qkv + (size_t)(q0b + w * 16 + lr) * SQKV + h * HEAD_DIM;
#pragma unroll
    for (int dt = 0; dt < 4; ++dt)
        qf[dt] = *(const bf16x8*)(qrow + dt * 32 + lg * 8);

    f32x4 o[8] = {};
    float m[4], l[4];
#pragma unroll
    for (int j = 0; j < 4; ++j) { m[j] = -3e38f; l[j] = 0.0f; }
    const float scale = 0.08838834764831845f;

    stageK(0, 0);
    asm volatile("s_waitcnt vmcnt(0)" ::: "memory");
    __builtin_amdgcn_sched_barrier(0);
    __builtin_amdgcn_s_barrier();

    int cur = 0;
    for (int t = 0; t < nt; ++t) {
        const int kb = t * 64;
        const bool pf = (t + 1 < nt);
        stageV(kb);
        if (pf) stageK(cur ^ 1, kb + 64);
        const bool act = (t < myNt);

        if (act) {
            f32x4 s[4] = {};
            __builtin_amdgcn_s_setprio(1);
#pragma unroll
            for (int ss = 0; ss < 4; ++ss) {
                const int r = ss * 16 + lr;
                const int sw = (r & 7) << 3;
#pragma unroll
                for (int dt = 0; dt < 4; ++dt) {
                    bf16x8 kf = *(const bf16x8*)&Kt[cur][r * 128 + ((dt * 32 + lg * 8) ^ sw)];
                    s[ss] = MFMA16(qf[dt], kf, s[ss]);
                }
            }
            __builtin_amdgcn_s_setprio(0);

            float al[4];
#pragma unroll
            for (int j = 0; j < 4; ++j) {
                const int qi = q0b + w * 16 + lg * 4 + j;
                const int prow = lg * 4 + j;
                const int psw = (prow & 7) << 3;
                float a[4];
#pragma unroll
                for (int ss = 0; ss < 4; ++ss)
                    a[ss] = s[ss][j] * scale + ((kb + ss * 16 + lr) > qi ? -1e9f : 0.0f);
                float mx = fmaxf(fmaxf(a[0], a[1]), fmaxf(a[2], a[3]));
                mx = fmaxf(mx, __shfl_xor(mx, 1));
                mx = fmaxf(mx, __shfl_xor(mx, 2));
                mx = fmaxf(mx, __shfl_xor(mx, 4));
                mx = fmaxf(mx, __shfl_xor(mx, 8));
                const float mn = fmaxf(m[j], mx);
                const float asc = __expf(m[j] - mn);
                float e0 = __expf(a[0] - mn), e1 = __expf(a[1] - mn);
                float e2 = __expf(a[2] - mn), e3 = __expf(a[3] - mn);
                float rs = (e0 + e1) + (e2 + e3);
                rs += __shfl_xor(rs, 1); rs += __shfl_xor(rs, 2);
                rs += __shfl_xor(rs, 4); rs += __shfl_xor(rs, 8);
                l[j] = l[j] * asc + rs;
                m[j] = mn;
                al[j] = asc;
                Pp[w8][prow * 64 + ((lr)      ^ psw)] = f2bu(e0);
                Pp[w8][prow * 64 + ((16 + lr) ^ psw)] = f2bu(e1);
                Pp[w8][prow * 64 + ((32 + lr) ^ psw)] = f2bu(e2);
                Pp[w8][prow * 64 + ((48 + lr) ^ psw)] = f2bu(e3);
            }
#pragma unroll
            for (int d2 = 0; d2 < 8; ++d2)
#pragma unroll
                for (int j = 0; j < 4; ++j) o[d2][j] *= al[j];
        }

        if (pf) { asm volatile("s_waitcnt vmcnt(2)" ::: "memory"); }
        else    { asm volatile("s_waitcnt vmcnt(0)" ::: "memory"); }
        __builtin_amdgcn_sched_barrier(0);
        __builtin_amdgcn_s_barrier();

        if (act) {
            asm volatile("s_waitcnt lgkmcnt(0)" ::: "memory");
            __builtin_amdgcn_sched_barrier(0);
            const int asw = (lr & 7) << 3;
            bf16x8 pa0 = *(const bf16x8*)&Pp[w8][lr * 64 + ((lg * 8)      ^ asw)];
            bf16x8 pa1 = *(const bf16x8*)&Pp[w8][lr * 64 + ((32 + lg * 8) ^ asw)];

            __builtin_amdgcn_s_setprio(1);
#pragma unroll
            for (int d2 = 0; d2 < 8; ++d2) {
                const int rv = d2 * 16 + lr;
                const int vsw = (rv & 7) << 3;
                bf16x8 vf0 = *(const bf16x8*)&Vt[rv * 64 + ((lg * 8)      ^ vsw)];
                bf16x8 vf1 = *(const bf16x8*)&Vt[rv * 64 + ((32 + lg * 8) ^ vsw)];
                o[d2] = MFMA16(pa0, vf0, o[d2]);
                o[d2] = MFMA16(pa1, vf1, o[d2]);
            }
            __builtin_amdgcn_s_setprio(0);
        }

        __builtin_amdgcn_s_barrier();
        cur ^= 1;
    }

#pragma unroll
    for (int j = 0; j < 4; ++j) {
        const float inv = 1.0f / l[j];
        bf16* dst = ctx + (size_t)(q0b + w * 16 + lg * 4 + j) * DIM + h * HEAD_DIM + lr;
#pragma unroll
        for (int d2 = 0; d2 < 8; ++d2)
            dst[d2 * 16] = __float2bfloat16(o[d2][j] * inv);
    }
}

// ---------------- host ----------------
extern "C" void kernel_launch(void* const* d_in, const int* in_sizes, int n_in,
                              void* d_out, int out_size, void* d_ws, size_t ws_size,
                              hipStream_t stream)
{
    const float* x   = (const float*)d_in[0];
    const float* fc  = (const float*)d_in[1];
    const float* fs  = (const float*)d_in[2];
    // d_in[3] = mask (unused; causal computed analytically)
    const float* wq  = (const float*)d_in[4];
    const float* wk  = (const float*)d_in[5];
    const float* wv  = (const float*)d_in[6];
    const float* wo  = (const float*)d_in[7];
    const float* w1  = (const float*)d_in[8];
    const float* w2  = (const float*)d_in[9];
    const float* w3  = (const float*)d_in[10];
    const float* anw = (const float*)d_in[11];
    const float* fnw = (const float*)d_in[12];
    float* out = (float*)d_out;

    char* p = (char*)d_ws;
    auto alloc = [&](size_t n) { char* r = p; p += (n + 255) & ~(size_t)255; return r; };
    bf16* wT  = (bf16*)alloc((size_t)HID * DIM * 2);     // reused per weight group
    bf16* hn  = (bf16*)alloc((size_t)SEQ * DIM * 2);     // dead after QKV GEMM
    bf16* qkv = (bf16*)alloc((size_t)SEQ * SQKV * 2);    // dead after attn
    bf16* vt  = (bf16*)alloc((size_t)SEQ * DIM * 2);
    bf16* ctx = (bf16*)alloc((size_t)SEQ * DIM * 2);
    bf16* fn  = (bf16*)alloc((size_t)SEQ * DIM * 2);
    float* h  = (float*)alloc((size_t)SEQ * DIM * 4);
    bf16* g   = (bf16*)alloc((size_t)SEQ * HID * 2);
    bf16* sk  = (bf16*)alloc((size_t)4 * SEQ * DIM * 2); // split-K bf16 partials (32MB)
    // w3^T aliases hn+qkv (both dead by the time it's written)
    bf16* w3T = hn;

    const int LDS256 = 131072;
    (void)hipFuncSetAttribute((const void*)gemm256_k<0>,
        hipFuncAttributeMaxDynamicSharedMemorySize, LDS256);
    (void)hipFuncSetAttribute((const void*)gemm256_k<3>,
        hipFuncAttributeMaxDynamicSharedMemorySize, LDS256);
    (void)hipFuncSetAttribute((const void*)gemm256_k<4>,
        hipFuncAttributeMaxDynamicSharedMemorySize, LDS256);

    rmsnorm_bf16_k<<<SEQ, 256, 0, stream>>>(x, anw, hn);

    // fused QKV: wT = [wq^T; wk^T; wv^T] (6144x2048) -> qkv[2048][6144]
    convT64q_k<<<dim3(DIM / 64, DIM / 64, 3), 256, 0, stream>>>(wq, wk, wv, wT);
    gemm256_k<0><<<(SEQ / 256) * (SQKV / 256), 512, LDS256, stream>>>(
        hn, wT, nullptr, qkv, SEQ, SQKV, DIM, SQKV / 256, (SEQ / 256) * (SQKV / 256), DIM);

    rope_qk_k<<<(SEQ * 1024) / 256, 256, 0, stream>>>(qkv, qkv + DIM, fc, fs);
    transpose_bf16_k<<<dim3(DIM / 32, SEQ / 32), 256, 0, stream>>>(qkv + 2 * DIM, SQKV, vt);

    attn_fwd_k<<<dim3(16, N_HEADS), 512, 0, stream>>>(qkv, vt, ctx);

    // h = x + ctx @ wo : split-K=4 (Ks=512) -> bf16 partials, fused reduce+residual+rmsnorm
    convT64_k<<<dim3(DIM / 64, DIM / 64), 256, 0, stream>>>(wo, wT, DIM, DIM);
    gemm256_k<3><<<(SEQ / 256) * (DIM / 256) * 4, 512, LDS256, stream>>>(
        ctx, wT, nullptr, sk, SEQ, DIM, DIM, DIM / 256, (SEQ / 256) * (DIM / 256), 512);
    rmsnorm4_k<<<SEQ, 256, 0, stream>>>(sk, x, fnw, h, fn);

    // fused FFN-up: g = silu(fn@w1) * (fn@w3), single GEMM over N'=16384
    convT64f_k<<<dim3(HID / 64, DIM / 64, 2), 256, 0, stream>>>(w1, w3, wT, w3T);
    gemm256_k<4><<<(SEQ / 256) * ((2 * HID) / 256), 512, LDS256, stream>>>(
        fn, wT, w3T, g, SEQ, 2 * HID, DIM, (2 * HID) / 256,
        (SEQ / 256) * ((2 * HID) / 256), DIM);

    // out = h + g @ w2 : split-K=4 (Ks=2048) -> bf16 partials, reduce+residual
    convT64_k<<<dim3(DIM / 64, HID / 64), 256, 0, stream>>>(w2, wT, HID, DIM);
    gemm256_k<3><<<(SEQ / 256) * (DIM / 256) * 4, 512, LDS256, stream>>>(
        g, wT, nullptr, sk, SEQ, DIM, HID, DIM / 256, (SEQ / 256) * (DIM / 256), 2048);
    reduce4_k<<<(SEQ * DIM / 8) / 256, 256, 0, stream>>>(sk, h, out);
}